// Round 10
// baseline (64.215 us; speedup 1.0000x reference)
//
#include <hip/hip_runtime.h>

typedef __attribute__((ext_vector_type(8))) short bf16x8;
typedef __attribute__((ext_vector_type(4))) float f32x4;

namespace {
constexpr int NB = 256, NT = 64, NA = 32, NH = 512, NE = 16;
constexpr int LDAu = 520;          // A_lds row stride (ushorts)

// workspace layout (bytes)
constexpr size_t W1P_OFF  = 0;
constexpr size_t W1P_SZ   = (size_t)NE * 32 * 64 * 16;         //    524,288
constexpr size_t W2AP_OFF = W1P_OFF + W1P_SZ;
constexpr size_t W2AP_SZ  = (size_t)NE * 16 * 32 * 64 * 16;    //  8,388,608
constexpr size_t W3P_OFF  = W2AP_OFF + W2AP_SZ;
constexpr size_t W3P_SZ   = (size_t)NE * 16 * 32 * 64 * 16;    //  8,388,608
constexpr size_t W2TP_OFF = W3P_OFF + W3P_SZ;
constexpr size_t W2TP_SZ  = (size_t)NE * NH * NH * 2;          //  8,388,608
constexpr size_t TAUC_OFF = W2TP_OFF + W2TP_SZ;
constexpr size_t TAUC_SZ  = (size_t)NB * NH * 4;               //    524,288
constexpr size_t PERM_OFF = TAUC_OFF + TAUC_SZ;
constexpr size_t WS_NEED  = PERM_OFF + (size_t)NB * 4;         // ~25.7 MiB
}

__device__ __forceinline__ unsigned f2bf(float x) {
    union { float f; unsigned u; } v; v.f = x;
    return (v.u + 0x7FFFu + ((v.u >> 16) & 1u)) >> 16;   // RNE, low 16 bits valid
}
__device__ __forceinline__ float bf2f(unsigned u) {   // low 16 bits = bf16
    union { unsigned u; float f; } v; v.u = u << 16;
    return v.f;
}
__device__ __forceinline__ f32x4 MFMA(bf16x8 a, bf16x8 b, f32x4 c) {
    return __builtin_amdgcn_mfma_f32_16x16x32_bf16(a, b, c, 0, 0, 0);
}

// ---------------------------------------------------------------------------
// pack_weights: f32 -> bf16. W1/W2a/W3 as MFMA-B fragments [cat][ks][nt][lane]
// (lane holds W[kbase+(lane>>4)*8+j][nt*16+(lane&15)], j=0..7). W2 tau-half
// (rows 512..1023) row-major bf16 [cat][k][c] for the tau GEMV.
// Block 0 additionally computes the cat-sorted permutation.
// ---------------------------------------------------------------------------
__global__ void pack_weights(const float* __restrict__ W1,
                             const float* __restrict__ W2,
                             const float* __restrict__ W3,
                             const int*   __restrict__ cat_ids,
                             unsigned char* __restrict__ ws)
{
    const int idx = blockIdx.x * 256 + threadIdx.x;
    constexpr int NF2 = NE * 16 * 32 * 64;    // 524,288  (W2 a_emb half)
    constexpr int NF3 = NE * 16 * 32 * 64;    // 524,288
    constexpr int NF1 = NE * 32 * 64;         //  32,768
    constexpr int NW2T = NE * NH * NH / 8;    // 524,288

    if (idx < NF2 + NF3 + NF1) {
        const float* src;
        uint4* dst;
        int fi, kbase;
        if (idx < NF2) {
            fi = idx;
            kbase = ((fi >> 11) & 15) * 32;                  // rows 0..511
            src = W2 + (size_t)(fi >> 15) * 1024 * NH;
            dst = (uint4*)(ws + W2AP_OFF);
        } else if (idx < NF2 + NF3) {
            fi = idx - NF2;
            kbase = ((fi >> 11) & 15) * 32;
            src = W3 + (size_t)(fi >> 15) * NH * NH;
            dst = (uint4*)(ws + W3P_OFF);
        } else {
            fi = idx - NF2 - NF3;
            kbase = 0;
            src = W1 + (size_t)(fi >> 11) * NA * NH;
            dst = (uint4*)(ws + W1P_OFF);
        }
        const int lane = fi & 63;
        const int nt   = (fi >> 6) & 31;
        const int k0   = kbase + ((lane >> 4) << 3);
        const int n    = nt * 16 + (lane & 15);
        unsigned rr[4];
        #pragma unroll
        for (int p = 0; p < 4; ++p) {
            const unsigned lo = f2bf(src[(size_t)(k0 + 2*p    ) * NH + n]);
            const unsigned hi = f2bf(src[(size_t)(k0 + 2*p + 1) * NH + n]);
            rr[p] = lo | (hi << 16);
        }
        uint4 r; r.x = rr[0]; r.y = rr[1]; r.z = rr[2]; r.w = rr[3];
        dst[fi] = r;
    } else if (idx < NF2 + NF3 + NF1 + NW2T) {
        const int p   = idx - (NF2 + NF3 + NF1);
        const int cat = p >> 15;
        const int rem = p & 32767;
        const int k   = rem >> 6;              // 0..511 tau-half row
        const int c0  = (rem & 63) << 3;
        const float* src =
            W2 + (size_t)cat * 1024 * NH + (size_t)(NH + k) * NH + c0;
        const float4 a = ((const float4*)src)[0];
        const float4 b = ((const float4*)src)[1];
        uint4 r;
        r.x = f2bf(a.x) | (f2bf(a.y) << 16);
        r.y = f2bf(a.z) | (f2bf(a.w) << 16);
        r.z = f2bf(b.x) | (f2bf(b.y) << 16);
        r.w = f2bf(b.z) | (f2bf(b.w) << 16);
        ((uint4*)(ws + W2TP_OFF))[p] = r;      // row-major [cat][k][c]
    }

    if (blockIdx.x == 0) {
        __shared__ int cs[NB];
        const int bb = threadIdx.x;
        cs[bb] = cat_ids[bb];
        __syncthreads();
        const int my = cs[bb];
        int rank = 0;
        #pragma unroll 8
        for (int i = 0; i < NB; ++i) {
            const int c = cs[i];
            rank += (c < my) || (c == my && i < bb);
        }
        ((int*)(ws + PERM_OFF))[rank] = bb;
    }
}

// ---------------------------------------------------------------------------
// tau_gemv: tauc[b][c] = b2[cat][c] + sum_k tau_b[k] * W2tau[cat][k][c].
// One block per b, 256 threads, each owns a col-pair via u32 loads.
// ---------------------------------------------------------------------------
__global__ __launch_bounds__(256)
void tau_gemv(const float* __restrict__ timesteps,
              const int*   __restrict__ cat_ids,
              const float* __restrict__ b2,
              unsigned char* __restrict__ ws)
{
    __shared__ float tau_s[NH];
    const int b   = blockIdx.x;
    const int tid = threadIdx.x;
    const int cat = cat_ids[b];
    const float t = timesteps[b];

    #pragma unroll
    for (int q = 0; q < 2; ++q) {
        const int k = tid + q * 256;
        const int i = k & 255;
        const float f = __expf(-(float)i * 0.036118981f);   // ln(1e4)/255
        tau_s[k] = (k < 256) ? __sinf(t * f) : __cosf(t * f);
    }
    __syncthreads();

    const unsigned* __restrict__ w =
        (const unsigned*)(ws + W2TP_OFF) + (size_t)cat * (NH * NH / 2) + tid;
    float s0a = 0.f, s1a = 0.f, s0b = 0.f, s1b = 0.f;
    #pragma unroll 8
    for (int k = 0; k < NH; k += 2) {
        const unsigned u0 = w[(size_t)k * 256];
        const unsigned u1 = w[(size_t)(k + 1) * 256];
        const float t0 = tau_s[k], t1 = tau_s[k + 1];
        s0a += t0 * bf2f(u0 & 0xffffu);  s1a += t0 * bf2f(u0 >> 16);
        s0b += t1 * bf2f(u1 & 0xffffu);  s1b += t1 * bf2f(u1 >> 16);
    }
    const int c = 2 * tid;
    float* tauc = (float*)(ws + TAUC_OFF) + (size_t)b * NH;
    tauc[c]     = s0a + s0b + b2[cat * NH + c];
    tauc[c + 1] = s1a + s1b + b2[cat * NH + c + 1];
}

// ---------------------------------------------------------------------------
// Fused MFMA kernel. Grid 256 (1 b per block/CU), 512 threads = 8 waves,
// wave tile 64 rows x 64 cols: every B-fragment loaded once per block, and
// each 4-ds_read A-fetch feeds 16 MFMAs. 32-step unified B-stream
// (16 W2a + 16 W3): asm depth-4 B pipeline (vmcnt(12) steady) + register
// double-buffered A-fragments (read k+1 before MFMAs of k).
// ---------------------------------------------------------------------------
__global__ __launch_bounds__(512, 2)
void me_enc_mfma8(const float* __restrict__ actions,
                  const int*   __restrict__ cat_ids,
                  const float* __restrict__ b1,
                  const float* __restrict__ b3,
                  const unsigned char* __restrict__ ws,
                  float* __restrict__ out)
{
    __shared__ unsigned short A0[NT * LDAu];   // 66,560 B (a_emb)
    __shared__ unsigned short A1[NT * LDAu];   // 66,560 B (swish)

    const int bid  = blockIdx.x;
    const int tid  = threadIdx.x;
    const int lane = tid & 63;
    const int wn   = tid >> 6;          // 0..7: 64-col slice
    const int lr   = lane & 15;
    const int lg   = lane >> 4;
    const int col0 = wn * 64;
    const bool loLane = (lane & 1) == 0;

    const int sidx = ((bid & 7) << 5) | (bid >> 3);   // same-cat -> same XCD
    const int* __restrict__ perm = (const int*)(ws + PERM_OFF);
    const int b   = perm[sidx];
    const int cat = cat_ids[b];

    const uint4* __restrict__ wp2 =
        (const uint4*)(ws + W2AP_OFF) + (size_t)cat * 16 * 2048 + (size_t)(4 * wn) * 64 + lane;
    const uint4* __restrict__ wp3 =
        (const uint4*)(ws + W3P_OFF) + (size_t)cat * 16 * 2048 + (size_t)(4 * wn) * 64 + lane;

    // ---- compiler-managed global loads (consumed before/at P1 or pinned) ---
    float bias1[4], bias3[4], tauc_i[4];
    const float* __restrict__ taucp = (const float*)(ws + TAUC_OFF) + (size_t)b * NH;
    #pragma unroll
    for (int j = 0; j < 4; ++j) {
        const int c = col0 + j * 16 + lr;
        bias1[j]  = b1[cat * NH + c];
        bias3[j]  = b3[cat * NH + c];
        tauc_i[j] = taucp[c];
    }
    const uint4* __restrict__ w1p =
        (const uint4*)(ws + W1P_OFF) + (size_t)cat * 2048 + (size_t)(4 * wn) * 64 + lane;
    uint4 w1f0 = w1p[0], w1f1 = w1p[64], w1f2 = w1p[128], w1f3 = w1p[192];

    bf16x8 aact0, aact1, aact2, aact3;
    {
        bf16x8 tmp[4];
        #pragma unroll
        for (int mt = 0; mt < 4; ++mt) {
            const float* ap = actions + ((size_t)b * NT + mt * 16 + lr) * NA + lg * 8;
            const float4 a0 = ((const float4*)ap)[0];
            const float4 a1 = ((const float4*)ap)[1];
            bf16x8 v;
            v[0] = (short)f2bf(a0.x); v[1] = (short)f2bf(a0.y);
            v[2] = (short)f2bf(a0.z); v[3] = (short)f2bf(a0.w);
            v[4] = (short)f2bf(a1.x); v[5] = (short)f2bf(a1.y);
            v[6] = (short)f2bf(a1.z); v[7] = (short)f2bf(a1.w);
            tmp[mt] = v;
        }
        aact0 = tmp[0]; aact1 = tmp[1]; aact2 = tmp[2]; aact3 = tmp[3];
    }
    // Pin SCALAR values consumed at/after the K-loop so the compiler's own
    // vmcnt waits for them land HERE, not inside the asm pipeline.
    // (Vector operands are illegal as asm inputs on hipcc — R9 lesson.)
    asm volatile("" :: "v"(bias1[0]), "v"(bias1[1]), "v"(bias1[2]), "v"(bias1[3]),
                       "v"(bias3[0]), "v"(bias3[1]), "v"(bias3[2]), "v"(bias3[3]),
                       "v"(tauc_i[0]), "v"(tauc_i[1]), "v"(tauc_i[2]), "v"(tauc_i[3]));

    // ---- B pipeline: 4 slots x 4 frags, asm-issued ----
    uint4 buf0_0, buf0_1, buf0_2, buf0_3,
          buf1_0, buf1_1, buf1_2, buf1_3,
          buf2_0, buf2_1, buf2_2, buf2_3,
          buf3_0, buf3_1, buf3_2, buf3_3;

#define LOADB(S, kk)                                                            \
    if ((kk) < 32) {                                                            \
        const char* bp_ = (const char*)(((kk) < 16)                             \
            ? (wp2 + (size_t)(kk) * 2048)                                       \
            : (wp3 + (size_t)((kk) - 16) * 2048));                              \
        asm volatile("global_load_dwordx4 %0, %4, off\n\t"                      \
                     "global_load_dwordx4 %1, %4, off offset:1024\n\t"          \
                     "global_load_dwordx4 %2, %4, off offset:2048\n\t"          \
                     "global_load_dwordx4 %3, %4, off offset:3072"              \
                     : "=&v"(buf##S##_0), "=&v"(buf##S##_1),                    \
                       "=&v"(buf##S##_2), "=&v"(buf##S##_3)                     \
                     : "v"(bp_));                                               \
    }

    LOADB(0, 0) LOADB(1, 1) LOADB(2, 2) LOADB(3, 3)

    f32x4 acc[4][4];

    // ---- P1: layer 1 -> A0 (packed u32 writes) ----
    #pragma unroll
    for (int j = 0; j < 4; ++j) {
        const f32x4 v = {bias1[j], bias1[j], bias1[j], bias1[j]};
        #pragma unroll
        for (int mt = 0; mt < 4; ++mt) acc[mt][j] = v;
    }
    {
        union { uint4 u; bf16x8 v; } u0, u1, u2, u3;
        u0.u = w1f0; u1.u = w1f1; u2.u = w1f2; u3.u = w1f3;
        acc[0][0]=MFMA(aact0,u0.v,acc[0][0]); acc[1][0]=MFMA(aact1,u0.v,acc[1][0]);
        acc[2][0]=MFMA(aact2,u0.v,acc[2][0]); acc[3][0]=MFMA(aact3,u0.v,acc[3][0]);
        acc[0][1]=MFMA(aact0,u1.v,acc[0][1]); acc[1][1]=MFMA(aact1,u1.v,acc[1][1]);
        acc[2][1]=MFMA(aact2,u1.v,acc[2][1]); acc[3][1]=MFMA(aact3,u1.v,acc[3][1]);
        acc[0][2]=MFMA(aact0,u2.v,acc[0][2]); acc[1][2]=MFMA(aact1,u2.v,acc[1][2]);
        acc[2][2]=MFMA(aact2,u2.v,acc[2][2]); acc[3][2]=MFMA(aact3,u2.v,acc[3][2]);
        acc[0][3]=MFMA(aact0,u3.v,acc[0][3]); acc[1][3]=MFMA(aact1,u3.v,acc[1][3]);
        acc[2][3]=MFMA(aact2,u3.v,acc[2][3]); acc[3][3]=MFMA(aact3,u3.v,acc[3][3]);
    }
    #pragma unroll
    for (int mt = 0; mt < 4; ++mt)
        #pragma unroll
        for (int j = 0; j < 4; ++j)
            #pragma unroll
            for (int r = 0; r < 4; ++r) {
                const float v  = acc[mt][j][r];
                const float vn = __shfl_xor(v, 1);
                if (loLane)
                    *(unsigned*)&A0[(mt*16 + lg*4 + r) * LDAu + col0 + j*16 + lr] =
                        f2bf(v) | (f2bf(vn) << 16);
            }

    // ---- init acc for layer 2 (tauc already includes b2 + tau@W2tau) ----
    #pragma unroll
    for (int j = 0; j < 4; ++j) {
        const f32x4 v = {tauc_i[j], tauc_i[j], tauc_i[j], tauc_i[j]};
        #pragma unroll
        for (int mt = 0; mt < 4; ++mt) acc[mt][j] = v;
    }

    asm volatile("s_waitcnt lgkmcnt(0)" ::: "memory");
    __builtin_amdgcn_sched_barrier(0);
    __builtin_amdgcn_s_barrier();          // a_emb visible to all waves
    __builtin_amdgcn_sched_barrier(0);

    // ---- A-fragment double buffer: fill afA for step 0 ----
    bf16x8 afA0, afA1, afA2, afA3, afB0, afB1, afB2, afB3;
    {
        const int ko_ = lg * 8;
        afA0 = *(const bf16x8*)&A0[(lr     ) * LDAu + ko_];
        afA1 = *(const bf16x8*)&A0[(lr + 16) * LDAu + ko_];
        afA2 = *(const bf16x8*)&A0[(lr + 32) * LDAu + ko_];
        afA3 = *(const bf16x8*)&A0[(lr + 48) * LDAu + ko_];
    }

#define MFMA16(AF, S) {                                                         \
    union { uint4 u; bf16x8 v; } u0_, u1_, u2_, u3_;                            \
    u0_.u = buf##S##_0; u1_.u = buf##S##_1;                                     \
    u2_.u = buf##S##_2; u3_.u = buf##S##_3;                                     \
    acc[0][0]=MFMA(AF##0,u0_.v,acc[0][0]); acc[1][0]=MFMA(AF##1,u0_.v,acc[1][0]); \
    acc[2][0]=MFMA(AF##2,u0_.v,acc[2][0]); acc[3][0]=MFMA(AF##3,u0_.v,acc[3][0]); \
    acc[0][1]=MFMA(AF##0,u1_.v,acc[0][1]); acc[1][1]=MFMA(AF##1,u1_.v,acc[1][1]); \
    acc[2][1]=MFMA(AF##2,u1_.v,acc[2][1]); acc[3][1]=MFMA(AF##3,u1_.v,acc[3][1]); \
    acc[0][2]=MFMA(AF##0,u2_.v,acc[0][2]); acc[1][2]=MFMA(AF##1,u2_.v,acc[1][2]); \
    acc[2][2]=MFMA(AF##2,u2_.v,acc[2][2]); acc[3][2]=MFMA(AF##3,u2_.v,acc[3][2]); \
    acc[0][3]=MFMA(AF##0,u3_.v,acc[0][3]); acc[1][3]=MFMA(AF##1,u3_.v,acc[1][3]); \
    acc[2][3]=MFMA(AF##2,u3_.v,acc[2][3]); acc[3][3]=MFMA(AF##3,u3_.v,acc[3][3]); }

#define STEPX(S, kk, VM, AFC, AFN)                                              \
    {                                                                           \
        asm volatile("s_waitcnt vmcnt(" #VM ")");                               \
        __builtin_amdgcn_sched_barrier(0);                                      \
        if (((kk) + 1) < 32 && ((kk) + 1) != 16) {                              \
            const unsigned short* Ab_ = (((kk) + 1) < 16) ? A0 : A1;            \
            const int kn_ = (((kk) + 1) & 15) * 32 + lg * 8;                    \
            AFN##0 = *(const bf16x8*)&Ab_[(lr     ) * LDAu + kn_];              \
            AFN##1 = *(const bf16x8*)&Ab_[(lr + 16) * LDAu + kn_];              \
            AFN##2 = *(const bf16x8*)&Ab_[(lr + 32) * LDAu + kn_];              \
            AFN##3 = *(const bf16x8*)&Ab_[(lr + 48) * LDAu + kn_];              \
        }                                                                       \
        MFMA16(AFC, S)                                                          \
        LOADB(S, (kk) + 4)                                                      \
    }

    // ---- layer 2: steps 0..15 (A0 @ W2a, acc starts at tauc) ----
    STEPX(0, 0,12,afA,afB) STEPX(1, 1,12,afB,afA) STEPX(2, 2,12,afA,afB) STEPX(3, 3,12,afB,afA)
    STEPX(0, 4,12,afA,afB) STEPX(1, 5,12,afB,afA) STEPX(2, 6,12,afA,afB) STEPX(3, 7,12,afB,afA)
    STEPX(0, 8,12,afA,afB) STEPX(1, 9,12,afB,afA) STEPX(2,10,12,afA,afB) STEPX(3,11,12,afB,afA)
    STEPX(0,12,12,afA,afB) STEPX(1,13,12,afB,afA) STEPX(2,14,12,afA,afB) STEPX(3,15,12,afB,afA)

    // ---- swish -> A1, acc = bias3, barrier, refill afA for step 16 ----
    #pragma unroll
    for (int mt = 0; mt < 4; ++mt)
        #pragma unroll
        for (int j = 0; j < 4; ++j)
            #pragma unroll
            for (int r = 0; r < 4; ++r) {
                const float h  = acc[mt][j][r];
                const float sw = h / (1.f + __expf(-h));
                const float swn = __shfl_xor(sw, 1);
                if (loLane)
                    *(unsigned*)&A1[(mt*16 + lg*4 + r) * LDAu + col0 + j*16 + lr] =
                        f2bf(sw) | (f2bf(swn) << 16);
            }
    #pragma unroll
    for (int j = 0; j < 4; ++j) {
        const f32x4 v = {bias3[j], bias3[j], bias3[j], bias3[j]};
        #pragma unroll
        for (int mt = 0; mt < 4; ++mt) acc[mt][j] = v;
    }
    asm volatile("s_waitcnt lgkmcnt(0)" ::: "memory");
    __builtin_amdgcn_sched_barrier(0);
    __builtin_amdgcn_s_barrier();          // swish visible (W3 loads in flight)
    __builtin_amdgcn_sched_barrier(0);
    {
        const int ko_ = lg * 8;
        afA0 = *(const bf16x8*)&A1[(lr     ) * LDAu + ko_];
        afA1 = *(const bf16x8*)&A1[(lr + 16) * LDAu + ko_];
        afA2 = *(const bf16x8*)&A1[(lr + 32) * LDAu + ko_];
        afA3 = *(const bf16x8*)&A1[(lr + 48) * LDAu + ko_];
    }

    // ---- layer 3: steps 16..31 (A1 @ W3, tail vmcnt 12/8/4/0) ----
    STEPX(0,16,12,afA,afB) STEPX(1,17,12,afB,afA) STEPX(2,18,12,afA,afB) STEPX(3,19,12,afB,afA)
    STEPX(0,20,12,afA,afB) STEPX(1,21,12,afB,afA) STEPX(2,22,12,afA,afB) STEPX(3,23,12,afB,afA)
    STEPX(0,24,12,afA,afB) STEPX(1,25,12,afB,afA) STEPX(2,26,12,afA,afB) STEPX(3,27,12,afB,afA)
    STEPX(0,28,12,afA,afB) STEPX(1,29, 8,afB,afA) STEPX(2,30, 4,afA,afB) STEPX(3,31, 0,afB,afA)

#undef STEPX
#undef MFMA16
#undef LOADB

    // ---- epilogue ----
    #pragma unroll
    for (int mt = 0; mt < 4; ++mt)
        #pragma unroll
        for (int j = 0; j < 4; ++j)
            #pragma unroll
            for (int r = 0; r < 4; ++r)
                out[((size_t)b * NT + mt*16 + lg*4 + r) * NH + col0 + j*16 + lr] =
                    acc[mt][j][r];
}

// ---------------------------------------------------------------------------
// Fallback (f32, no workspace) if ws is too small.
// ---------------------------------------------------------------------------
__global__ __launch_bounds__(512, 2)
void me_enc_fused(const float* __restrict__ actions,
                  const float* __restrict__ timesteps,
                  const int*   __restrict__ cat_ids,
                  const float* __restrict__ W1,
                  const float* __restrict__ b1,
                  const float* __restrict__ W2,
                  const float* __restrict__ b2,
                  const float* __restrict__ W3,
                  const float* __restrict__ b3,
                  float* __restrict__ out)
{
    __shared__ float tau_s[NH];
    __shared__ float tauc_s[NH];
    __shared__ float act_s[16 * NA];
    __shared__ float buf_s[16][NH];

    const int b   = blockIdx.x;
    const int tid = threadIdx.x;
    const int cat = cat_ids[b];
    const float t = timesteps[b];

    const float* __restrict__ W1c = W1 + (size_t)cat * NA * NH;
    const float* __restrict__ W2c = W2 + (size_t)cat * 2 * NH * NH;
    const float* __restrict__ W2t = W2c + (size_t)NH * NH;
    const float* __restrict__ W3c = W3 + (size_t)cat * NH * NH;

    {
        const int i = tid & 255;
        const float f   = __expf(-(float)i * 0.036118981f);
        const float ang = t * f;
        tau_s[tid] = (tid < 256) ? __sinf(ang) : __cosf(ang);
    }
    __syncthreads();
    {
        float c0 = 0.f;
        for (int k = 0; k < NH; ++k)
            c0 += tau_s[k] * W2t[(size_t)k * NH + tid];
        tauc_s[tid] = b2[cat * NH + tid] + c0;
    }
    const float b1v = b1[cat * NH + tid];
    const int j2  = tid & 255;
    const int tl0 = (tid >> 8) * 8;
    const float b3v0 = b3[cat * NH + j2];
    const float b3v1 = b3[cat * NH + j2 + 256];
    const size_t obase = (size_t)b * NT * NH;
    float acc0[8], acc1[8];

    for (int t0 = 0; t0 < NT; t0 += 16) {
        act_s[tid] = actions[(size_t)b*NT*NA + (size_t)(t0 + (tid >> 5))*NA + (tid & 31)];
        __syncthreads();
        {
            float a_[16];
            #pragma unroll
            for (int l = 0; l < 16; ++l) a_[l] = b1v;
            for (int a = 0; a < NA; ++a) {
                const float w = W1c[(size_t)a * NH + tid];
                #pragma unroll
                for (int l = 0; l < 16; ++l) a_[l] += act_s[l*NA + a] * w;
            }
            #pragma unroll
            for (int l = 0; l < 16; ++l) buf_s[l][tid] = a_[l];
        }
        __syncthreads();
        {
            const float tc0 = tauc_s[j2], tc1 = tauc_s[j2 + 256];
            #pragma unroll
            for (int l = 0; l < 8; ++l) { acc0[l] = tc0; acc1[l] = tc1; }
            for (int k = 0; k < NH; ++k) {
                const float wa = W2c[(size_t)k*NH + j2];
                const float wb = W2c[(size_t)k*NH + j2 + 256];
                #pragma unroll
                for (int l = 0; l < 8; ++l) {
                    const float av = buf_s[tl0 + l][k];
                    acc0[l] += av * wa; acc1[l] += av * wb;
                }
            }
        }
        __syncthreads();
        #pragma unroll
        for (int l = 0; l < 8; ++l) {
            buf_s[tl0 + l][j2]       = acc0[l] / (1.f + __expf(-acc0[l]));
            buf_s[tl0 + l][j2 + 256] = acc1[l] / (1.f + __expf(-acc1[l]));
        }
        __syncthreads();
        {
            #pragma unroll
            for (int l = 0; l < 8; ++l) { acc0[l] = b3v0; acc1[l] = b3v1; }
            for (int k = 0; k < NH; ++k) {
                const float wa = W3c[(size_t)k*NH + j2];
                const float wb = W3c[(size_t)k*NH + j2 + 256];
                #pragma unroll
                for (int l = 0; l < 8; ++l) {
                    const float av = buf_s[tl0 + l][k];
                    acc0[l] += av * wa; acc1[l] += av * wb;
                }
            }
            #pragma unroll
            for (int l = 0; l < 8; ++l) {
                out[obase + (size_t)(t0 + tl0 + l)*NH + j2]       = acc0[l];
                out[obase + (size_t)(t0 + tl0 + l)*NH + j2 + 256] = acc1[l];
            }
        }
        __syncthreads();
    }
}

extern "C" void kernel_launch(void* const* d_in, const int* in_sizes, int n_in,
                              void* d_out, int out_size, void* d_ws, size_t ws_size,
                              hipStream_t stream)
{
    const float* actions   = (const float*)d_in[0];
    const float* timesteps = (const float*)d_in[1];
    const int*   cat_ids   = (const int*)  d_in[2];
    const float* W1 = (const float*)d_in[3];
    const float* b1 = (const float*)d_in[4];
    const float* W2 = (const float*)d_in[5];
    const float* b2 = (const float*)d_in[6];
    const float* W3 = (const float*)d_in[7];
    const float* b3 = (const float*)d_in[8];
    float* out = (float*)d_out;

    (void)in_sizes; (void)n_in; (void)out_size;

    if (ws_size >= WS_NEED) {
        unsigned char* ws = (unsigned char*)d_ws;
        constexpr int PACK_THREADS =
            NE*16*32*64 + NE*16*32*64 + NE*32*64 + NE*NH*NH/8;
        pack_weights<<<(PACK_THREADS + 255)/256, 256, 0, stream>>>(W1, W2, W3, cat_ids, ws);
        tau_gemv<<<NB, 256, 0, stream>>>(timesteps, cat_ids, b2, ws);
        me_enc_mfma8<<<NB, 512, 0, stream>>>(actions, cat_ids, b1, b3, ws, out);
    } else {
        me_enc_fused<<<NB, 512, 0, stream>>>(actions, timesteps, cat_ids,
                                             W1, b1, W2, b2, W3, b3, out);
    }
}

// Round 11
// 63.216 us; speedup vs baseline: 1.0158x; 1.0158x over previous
//
#include <hip/hip_runtime.h>

typedef __attribute__((ext_vector_type(8))) short bf16x8;
typedef __attribute__((ext_vector_type(4))) float f32x4;

namespace {
constexpr int NB = 256, NT = 64, NA = 32, NH = 512, NE = 16;
constexpr int ATS = 64 * 40;       // ushorts per ks-tile of A (row pad 40)

// workspace layout (bytes)
constexpr size_t W1P_OFF  = 0;
constexpr size_t W1P_SZ   = (size_t)NE * 32 * 64 * 16;         //    524,288
constexpr size_t W2AP_OFF = W1P_OFF + W1P_SZ;
constexpr size_t W2AP_SZ  = (size_t)NE * 16 * 32 * 64 * 16;    //  8,388,608
constexpr size_t W3P_OFF  = W2AP_OFF + W2AP_SZ;
constexpr size_t W3P_SZ   = (size_t)NE * 16 * 32 * 64 * 16;    //  8,388,608
constexpr size_t W2TP_OFF = W3P_OFF + W3P_SZ;
constexpr size_t W2TP_SZ  = (size_t)NE * NH * NH * 2;          //  8,388,608
constexpr size_t TAUC_OFF = W2TP_OFF + W2TP_SZ;
constexpr size_t TAUC_SZ  = (size_t)NB * NH * 4;               //    524,288
constexpr size_t PERM_OFF = TAUC_OFF + TAUC_SZ;
constexpr size_t WS_NEED  = PERM_OFF + (size_t)NB * 4;         // ~25.7 MiB
}

__device__ __forceinline__ unsigned f2bf(float x) {
    union { float f; unsigned u; } v; v.f = x;
    return (v.u + 0x7FFFu + ((v.u >> 16) & 1u)) >> 16;   // RNE, low 16 bits valid
}
__device__ __forceinline__ float bf2f(unsigned u) {   // low 16 bits = bf16
    union { unsigned u; float f; } v; v.u = u << 16;
    return v.f;
}
__device__ __forceinline__ f32x4 MFMA(bf16x8 a, bf16x8 b, f32x4 c) {
    return __builtin_amdgcn_mfma_f32_16x16x32_bf16(a, b, c, 0, 0, 0);
}

// ---------------------------------------------------------------------------
// pack_weights: f32 -> bf16. W1/W2a/W3 as MFMA-B fragments [cat][ks][nt][lane]
// (lane holds W[kbase+(lane>>4)*8+j][nt*16+(lane&15)], j=0..7). W2 tau-half
// (rows 512..1023) row-major bf16 [cat][k][c] for the tau GEMV.
// Block 0 additionally computes the cat-sorted permutation.
// ---------------------------------------------------------------------------
__global__ void pack_weights(const float* __restrict__ W1,
                             const float* __restrict__ W2,
                             const float* __restrict__ W3,
                             const int*   __restrict__ cat_ids,
                             unsigned char* __restrict__ ws)
{
    const int idx = blockIdx.x * 256 + threadIdx.x;
    constexpr int NF2 = NE * 16 * 32 * 64;    // 524,288  (W2 a_emb half)
    constexpr int NF3 = NE * 16 * 32 * 64;    // 524,288
    constexpr int NF1 = NE * 32 * 64;         //  32,768
    constexpr int NW2T = NE * NH * NH / 8;    // 524,288

    if (idx < NF2 + NF3 + NF1) {
        const float* src;
        uint4* dst;
        int fi, kbase;
        if (idx < NF2) {
            fi = idx;
            kbase = ((fi >> 11) & 15) * 32;                  // rows 0..511
            src = W2 + (size_t)(fi >> 15) * 1024 * NH;
            dst = (uint4*)(ws + W2AP_OFF);
        } else if (idx < NF2 + NF3) {
            fi = idx - NF2;
            kbase = ((fi >> 11) & 15) * 32;
            src = W3 + (size_t)(fi >> 15) * NH * NH;
            dst = (uint4*)(ws + W3P_OFF);
        } else {
            fi = idx - NF2 - NF3;
            kbase = 0;
            src = W1 + (size_t)(fi >> 11) * NA * NH;
            dst = (uint4*)(ws + W1P_OFF);
        }
        const int lane = fi & 63;
        const int nt   = (fi >> 6) & 31;
        const int k0   = kbase + ((lane >> 4) << 3);
        const int n    = nt * 16 + (lane & 15);
        unsigned rr[4];
        #pragma unroll
        for (int p = 0; p < 4; ++p) {
            const unsigned lo = f2bf(src[(size_t)(k0 + 2*p    ) * NH + n]);
            const unsigned hi = f2bf(src[(size_t)(k0 + 2*p + 1) * NH + n]);
            rr[p] = lo | (hi << 16);
        }
        uint4 r; r.x = rr[0]; r.y = rr[1]; r.z = rr[2]; r.w = rr[3];
        dst[fi] = r;
    } else if (idx < NF2 + NF3 + NF1 + NW2T) {
        const int p   = idx - (NF2 + NF3 + NF1);
        const int cat = p >> 15;
        const int rem = p & 32767;
        const int k   = rem >> 6;              // 0..511 tau-half row
        const int c0  = (rem & 63) << 3;
        const float* src =
            W2 + (size_t)cat * 1024 * NH + (size_t)(NH + k) * NH + c0;
        const float4 a = ((const float4*)src)[0];
        const float4 b = ((const float4*)src)[1];
        uint4 r;
        r.x = f2bf(a.x) | (f2bf(a.y) << 16);
        r.y = f2bf(a.z) | (f2bf(a.w) << 16);
        r.z = f2bf(b.x) | (f2bf(b.y) << 16);
        r.w = f2bf(b.z) | (f2bf(b.w) << 16);
        ((uint4*)(ws + W2TP_OFF))[p] = r;      // row-major [cat][k][c]
    }

    if (blockIdx.x == 0) {
        __shared__ int cs[NB];
        const int bb = threadIdx.x;
        cs[bb] = cat_ids[bb];
        __syncthreads();
        const int my = cs[bb];
        int rank = 0;
        #pragma unroll 8
        for (int i = 0; i < NB; ++i) {
            const int c = cs[i];
            rank += (c < my) || (c == my && i < bb);
        }
        ((int*)(ws + PERM_OFF))[rank] = bb;
    }
}

// ---------------------------------------------------------------------------
// tau_gemv: tauc[b][c] = b2[cat][c] + sum_k tau_b[k] * W2tau[cat][k][c].
// One block per b, 256 threads, each owns a col-pair via u32 loads.
// ---------------------------------------------------------------------------
__global__ __launch_bounds__(256)
void tau_gemv(const float* __restrict__ timesteps,
              const int*   __restrict__ cat_ids,
              const float* __restrict__ b2,
              unsigned char* __restrict__ ws)
{
    __shared__ float tau_s[NH];
    const int b   = blockIdx.x;
    const int tid = threadIdx.x;
    const int cat = cat_ids[b];
    const float t = timesteps[b];

    #pragma unroll
    for (int q = 0; q < 2; ++q) {
        const int k = tid + q * 256;
        const int i = k & 255;
        const float f = __expf(-(float)i * 0.036118981f);   // ln(1e4)/255
        tau_s[k] = (k < 256) ? __sinf(t * f) : __cosf(t * f);
    }
    __syncthreads();

    const unsigned* __restrict__ w =
        (const unsigned*)(ws + W2TP_OFF) + (size_t)cat * (NH * NH / 2) + tid;
    float s0a = 0.f, s1a = 0.f, s0b = 0.f, s1b = 0.f;
    #pragma unroll 8
    for (int k = 0; k < NH; k += 2) {
        const unsigned u0 = w[(size_t)k * 256];
        const unsigned u1 = w[(size_t)(k + 1) * 256];
        const float t0 = tau_s[k], t1 = tau_s[k + 1];
        s0a += t0 * bf2f(u0 & 0xffffu);  s1a += t0 * bf2f(u0 >> 16);
        s0b += t1 * bf2f(u1 & 0xffffu);  s1b += t1 * bf2f(u1 >> 16);
    }
    const int c = 2 * tid;
    float* tauc = (float*)(ws + TAUC_OFF) + (size_t)b * NH;
    tauc[c]     = s0a + s0b + b2[cat * NH + c];
    tauc[c + 1] = s1a + s1b + b2[cat * NH + c + 1];
}

// ---------------------------------------------------------------------------
// Fused MFMA kernel. Grid 256 (1 b per block/CU), 1024 threads = 16 waves,
// wave grid 1x16 (wave = 64 rows x 32 cols): every B-fragment loaded exactly
// once per block, 4 waves/SIMD. A in LDS as [ks][64 rows][40] ushort tiles:
// bank = (20*lr + 4*lg) % 32 -> exact 2-way (free); wave wn writes exactly
// ks-tile wn. 32-step B-stream (16 W2a + 16 W3), asm depth-5 pipeline,
// vmcnt(8) steady / 6,4,2,0 tail. Swish in place (single A buffer, 82 KB).
// ---------------------------------------------------------------------------
__global__ __launch_bounds__(1024, 4)
void me_enc_mfma9(const float* __restrict__ actions,
                  const int*   __restrict__ cat_ids,
                  const float* __restrict__ b1,
                  const float* __restrict__ b3,
                  const unsigned char* __restrict__ ws,
                  float* __restrict__ out)
{
    __shared__ unsigned short A_lds[16 * ATS];   // 81,920 B

    const int bid  = blockIdx.x;
    const int tid  = threadIdx.x;
    const int lane = tid & 63;
    const int wn   = tid >> 6;          // 0..15: 32-col slice (= own ks tile)
    const int lr   = lane & 15;
    const int lg   = lane >> 4;
    const int col0 = wn * 32;
    const bool loLane = (lane & 1) == 0;

    const int sidx = ((bid & 7) << 5) | (bid >> 3);   // same-cat -> same XCD
    const int* __restrict__ perm = (const int*)(ws + PERM_OFF);
    const int b   = perm[sidx];
    const int cat = cat_ids[b];

    const uint4* __restrict__ wp2 =
        (const uint4*)(ws + W2AP_OFF) + (size_t)cat * 16 * 2048 + (size_t)(2 * wn) * 64 + lane;
    const uint4* __restrict__ wp3 =
        (const uint4*)(ws + W3P_OFF) + (size_t)cat * 16 * 2048 + (size_t)(2 * wn) * 64 + lane;

    // ---- compiler-managed global loads ----
    float bias1[2], bias3[2], tauc_i[2];
    const float* __restrict__ taucp = (const float*)(ws + TAUC_OFF) + (size_t)b * NH;
    #pragma unroll
    for (int j = 0; j < 2; ++j) {
        const int c = col0 + j * 16 + lr;
        bias1[j]  = b1[cat * NH + c];
        bias3[j]  = b3[cat * NH + c];
        tauc_i[j] = taucp[c];
    }
    const uint4* __restrict__ w1p =
        (const uint4*)(ws + W1P_OFF) + (size_t)cat * 2048 + (size_t)(2 * wn) * 64 + lane;
    const uint4 w1f0 = w1p[0];
    const uint4 w1f1 = w1p[64];

    bf16x8 aact0, aact1, aact2, aact3;
    {
        bf16x8 tmp[4];
        #pragma unroll
        for (int mt = 0; mt < 4; ++mt) {
            const float* ap = actions + ((size_t)b * NT + mt * 16 + lr) * NA + lg * 8;
            const float4 a0 = ((const float4*)ap)[0];
            const float4 a1 = ((const float4*)ap)[1];
            bf16x8 v;
            v[0] = (short)f2bf(a0.x); v[1] = (short)f2bf(a0.y);
            v[2] = (short)f2bf(a0.z); v[3] = (short)f2bf(a0.w);
            v[4] = (short)f2bf(a1.x); v[5] = (short)f2bf(a1.y);
            v[6] = (short)f2bf(a1.z); v[7] = (short)f2bf(a1.w);
            tmp[mt] = v;
        }
        aact0 = tmp[0]; aact1 = tmp[1]; aact2 = tmp[2]; aact3 = tmp[3];
    }
    // Pin scalars consumed at/after the K-loop (scalar-only: R9 lesson).
    asm volatile("" :: "v"(bias3[0]), "v"(bias3[1]),
                       "v"(tauc_i[0]), "v"(tauc_i[1]));

    // ---- B pipeline: 5 slots x 2 frags, asm-issued ----
    uint4 buf0_0, buf0_1, buf1_0, buf1_1, buf2_0, buf2_1,
          buf3_0, buf3_1, buf4_0, buf4_1;

#define LOADB(S, kk)                                                            \
    if ((kk) < 32) {                                                            \
        const char* bp_ = (const char*)(((kk) < 16)                             \
            ? (wp2 + (size_t)(kk) * 2048)                                       \
            : (wp3 + (size_t)((kk) - 16) * 2048));                              \
        asm volatile("global_load_dwordx4 %0, %2, off\n\t"                      \
                     "global_load_dwordx4 %1, %2, off offset:1024"              \
                     : "=&v"(buf##S##_0), "=&v"(buf##S##_1)                     \
                     : "v"(bp_));                                               \
    }

    LOADB(0, 0) LOADB(1, 1)

    f32x4 acc[4][2];

    // ---- P1: layer 1 -> A_lds (packed u32 writes into own ks-tile) ----
    #pragma unroll
    for (int j = 0; j < 2; ++j) {
        const f32x4 v = {bias1[j], bias1[j], bias1[j], bias1[j]};
        #pragma unroll
        for (int mt = 0; mt < 4; ++mt) acc[mt][j] = v;
    }
    {
        union { uint4 u; bf16x8 v; } u0, u1;
        u0.u = w1f0; u1.u = w1f1;
        acc[0][0]=MFMA(aact0,u0.v,acc[0][0]); acc[1][0]=MFMA(aact1,u0.v,acc[1][0]);
        acc[2][0]=MFMA(aact2,u0.v,acc[2][0]); acc[3][0]=MFMA(aact3,u0.v,acc[3][0]);
        acc[0][1]=MFMA(aact0,u1.v,acc[0][1]); acc[1][1]=MFMA(aact1,u1.v,acc[1][1]);
        acc[2][1]=MFMA(aact2,u1.v,acc[2][1]); acc[3][1]=MFMA(aact3,u1.v,acc[3][1]);
    }
    unsigned* __restrict__ A32 = (unsigned*)A_lds;
    #pragma unroll
    for (int mt = 0; mt < 4; ++mt)
        #pragma unroll
        for (int j = 0; j < 2; ++j)
            #pragma unroll
            for (int r = 0; r < 4; ++r) {
                const float v  = acc[mt][j][r];
                const float vn = __shfl_xor(v, 1);
                if (loLane)
                    A32[(wn * ATS + (mt*16 + lg*4 + r) * 40 + j*16 + lr) >> 1] =
                        f2bf(v) | (f2bf(vn) << 16);
            }

    LOADB(2, 2) LOADB(3, 3) LOADB(4, 4)

    // ---- init acc for layer 2 (tauc already includes b2 + tau@W2tau) ----
    #pragma unroll
    for (int j = 0; j < 2; ++j) {
        const f32x4 v = {tauc_i[j], tauc_i[j], tauc_i[j], tauc_i[j]};
        #pragma unroll
        for (int mt = 0; mt < 4; ++mt) acc[mt][j] = v;
    }

    asm volatile("s_waitcnt lgkmcnt(0)" ::: "memory");
    __builtin_amdgcn_sched_barrier(0);
    __builtin_amdgcn_s_barrier();          // a_emb visible to all waves
    __builtin_amdgcn_sched_barrier(0);

#define STEPX(S, kk, VM)                                                        \
    {                                                                           \
        asm volatile("s_waitcnt vmcnt(" #VM ")");                               \
        __builtin_amdgcn_sched_barrier(0);                                      \
        const int ko_ = ((kk) & 15) * ATS + lg * 8;                             \
        const bf16x8 af0 = *(const bf16x8*)&A_lds[ko_ + (lr     ) * 40];        \
        const bf16x8 af1 = *(const bf16x8*)&A_lds[ko_ + (lr + 16) * 40];        \
        const bf16x8 af2 = *(const bf16x8*)&A_lds[ko_ + (lr + 32) * 40];        \
        const bf16x8 af3 = *(const bf16x8*)&A_lds[ko_ + (lr + 48) * 40];        \
        union { uint4 u; bf16x8 v; } w0_, w1_;                                  \
        w0_.u = buf##S##_0; w1_.u = buf##S##_1;                                 \
        acc[0][0] = MFMA(af0, w0_.v, acc[0][0]);                                \
        acc[1][0] = MFMA(af1, w0_.v, acc[1][0]);                                \
        acc[2][0] = MFMA(af2, w0_.v, acc[2][0]);                                \
        acc[3][0] = MFMA(af3, w0_.v, acc[3][0]);                                \
        acc[0][1] = MFMA(af0, w1_.v, acc[0][1]);                                \
        acc[1][1] = MFMA(af1, w1_.v, acc[1][1]);                                \
        acc[2][1] = MFMA(af2, w1_.v, acc[2][1]);                                \
        acc[3][1] = MFMA(af3, w1_.v, acc[3][1]);                                \
        LOADB(S, (kk) + 5)                                                      \
    }

    // ---- layer 2: steps 0..15 (A @ W2a, acc starts at tauc) ----
    STEPX(0, 0,8) STEPX(1, 1,8) STEPX(2, 2,8) STEPX(3, 3,8) STEPX(4, 4,8)
    STEPX(0, 5,8) STEPX(1, 6,8) STEPX(2, 7,8) STEPX(3, 8,8) STEPX(4, 9,8)
    STEPX(0,10,8) STEPX(1,11,8) STEPX(2,12,8) STEPX(3,13,8) STEPX(4,14,8)
    STEPX(0,15,8)

    // ---- swish in place: all reads done -> barrier -> write -> barrier ----
    asm volatile("s_waitcnt lgkmcnt(0)" ::: "memory");
    __builtin_amdgcn_sched_barrier(0);
    __builtin_amdgcn_s_barrier();          // all waves done reading a_emb
    __builtin_amdgcn_sched_barrier(0);
    #pragma unroll
    for (int mt = 0; mt < 4; ++mt)
        #pragma unroll
        for (int j = 0; j < 2; ++j)
            #pragma unroll
            for (int r = 0; r < 4; ++r) {
                const float h  = acc[mt][j][r];
                const float sw = h / (1.f + __expf(-h));
                const float swn = __shfl_xor(sw, 1);
                if (loLane)
                    A32[(wn * ATS + (mt*16 + lg*4 + r) * 40 + j*16 + lr) >> 1] =
                        f2bf(sw) | (f2bf(swn) << 16);
            }
    #pragma unroll
    for (int j = 0; j < 2; ++j) {
        const f32x4 v = {bias3[j], bias3[j], bias3[j], bias3[j]};
        #pragma unroll
        for (int mt = 0; mt < 4; ++mt) acc[mt][j] = v;
    }
    asm volatile("s_waitcnt lgkmcnt(0)" ::: "memory");
    __builtin_amdgcn_sched_barrier(0);
    __builtin_amdgcn_s_barrier();          // swish visible (W3 loads in flight)
    __builtin_amdgcn_sched_barrier(0);

    // ---- layer 3: steps 16..31 (A @ W3), tail vmcnt 6/4/2/0 ----
    STEPX(1,16,8) STEPX(2,17,8) STEPX(3,18,8) STEPX(4,19,8) STEPX(0,20,8)
    STEPX(1,21,8) STEPX(2,22,8) STEPX(3,23,8) STEPX(4,24,8) STEPX(0,25,8)
    STEPX(1,26,8) STEPX(2,27,8) STEPX(3,28,6) STEPX(4,29,4) STEPX(0,30,2)
    STEPX(1,31,0)

#undef STEPX
#undef LOADB

    // ---- epilogue ----
    #pragma unroll
    for (int mt = 0; mt < 4; ++mt)
        #pragma unroll
        for (int j = 0; j < 2; ++j)
            #pragma unroll
            for (int r = 0; r < 4; ++r)
                out[((size_t)b * NT + mt*16 + lg*4 + r) * NH + col0 + j*16 + lr] =
                    acc[mt][j][r];
}

// ---------------------------------------------------------------------------
// Fallback (f32, no workspace) if ws is too small.
// ---------------------------------------------------------------------------
__global__ __launch_bounds__(512, 2)
void me_enc_fused(const float* __restrict__ actions,
                  const float* __restrict__ timesteps,
                  const int*   __restrict__ cat_ids,
                  const float* __restrict__ W1,
                  const float* __restrict__ b1,
                  const float* __restrict__ W2,
                  const float* __restrict__ b2,
                  const float* __restrict__ W3,
                  const float* __restrict__ b3,
                  float* __restrict__ out)
{
    __shared__ float tau_s[NH];
    __shared__ float tauc_s[NH];
    __shared__ float act_s[16 * NA];
    __shared__ float buf_s[16][NH];

    const int b   = blockIdx.x;
    const int tid = threadIdx.x;
    const int cat = cat_ids[b];
    const float t = timesteps[b];

    const float* __restrict__ W1c = W1 + (size_t)cat * NA * NH;
    const float* __restrict__ W2c = W2 + (size_t)cat * 2 * NH * NH;
    const float* __restrict__ W2t = W2c + (size_t)NH * NH;
    const float* __restrict__ W3c = W3 + (size_t)cat * NH * NH;

    {
        const int i = tid & 255;
        const float f   = __expf(-(float)i * 0.036118981f);
        const float ang = t * f;
        tau_s[tid] = (tid < 256) ? __sinf(ang) : __cosf(ang);
    }
    __syncthreads();
    {
        float c0 = 0.f;
        for (int k = 0; k < NH; ++k)
            c0 += tau_s[k] * W2t[(size_t)k * NH + tid];
        tauc_s[tid] = b2[cat * NH + tid] + c0;
    }
    const float b1v = b1[cat * NH + tid];
    const int j2  = tid & 255;
    const int tl0 = (tid >> 8) * 8;
    const float b3v0 = b3[cat * NH + j2];
    const float b3v1 = b3[cat * NH + j2 + 256];
    const size_t obase = (size_t)b * NT * NH;
    float acc0[8], acc1[8];

    for (int t0 = 0; t0 < NT; t0 += 16) {
        act_s[tid] = actions[(size_t)b*NT*NA + (size_t)(t0 + (tid >> 5))*NA + (tid & 31)];
        __syncthreads();
        {
            float a_[16];
            #pragma unroll
            for (int l = 0; l < 16; ++l) a_[l] = b1v;
            for (int a = 0; a < NA; ++a) {
                const float w = W1c[(size_t)a * NH + tid];
                #pragma unroll
                for (int l = 0; l < 16; ++l) a_[l] += act_s[l*NA + a] * w;
            }
            #pragma unroll
            for (int l = 0; l < 16; ++l) buf_s[l][tid] = a_[l];
        }
        __syncthreads();
        {
            const float tc0 = tauc_s[j2], tc1 = tauc_s[j2 + 256];
            #pragma unroll
            for (int l = 0; l < 8; ++l) { acc0[l] = tc0; acc1[l] = tc1; }
            for (int k = 0; k < NH; ++k) {
                const float wa = W2c[(size_t)k*NH + j2];
                const float wb = W2c[(size_t)k*NH + j2 + 256];
                #pragma unroll
                for (int l = 0; l < 8; ++l) {
                    const float av = buf_s[tl0 + l][k];
                    acc0[l] += av * wa; acc1[l] += av * wb;
                }
            }
        }
        __syncthreads();
        #pragma unroll
        for (int l = 0; l < 8; ++l) {
            buf_s[tl0 + l][j2]       = acc0[l] / (1.f + __expf(-acc0[l]));
            buf_s[tl0 + l][j2 + 256] = acc1[l] / (1.f + __expf(-acc1[l]));
        }
        __syncthreads();
        {
            #pragma unroll
            for (int l = 0; l < 8; ++l) { acc0[l] = b3v0; acc1[l] = b3v1; }
            for (int k = 0; k < NH; ++k) {
                const float wa = W3c[(size_t)k*NH + j2];
                const float wb = W3c[(size_t)k*NH + j2 + 256];
                #pragma unroll
                for (int l = 0; l < 8; ++l) {
                    const float av = buf_s[tl0 + l][k];
                    acc0[l] += av * wa; acc1[l] += av * wb;
                }
            }
            #pragma unroll
            for (int l = 0; l < 8; ++l) {
                out[obase + (size_t)(t0 + tl0 + l)*NH + j2]       = acc0[l];
                out[obase + (size_t)(t0 + tl0 + l)*NH + j2 + 256] = acc1[l];
            }
        }
        __syncthreads();
    }
}

extern "C" void kernel_launch(void* const* d_in, const int* in_sizes, int n_in,
                              void* d_out, int out_size, void* d_ws, size_t ws_size,
                              hipStream_t stream)
{
    const float* actions   = (const float*)d_in[0];
    const float* timesteps = (const float*)d_in[1];
    const int*   cat_ids   = (const int*)  d_in[2];
    const float* W1 = (const float*)d_in[3];
    const float* b1 = (const float*)d_in[4];
    const float* W2 = (const float*)d_in[5];
    const float* b2 = (const float*)d_in[6];
    const float* W3 = (const float*)d_in[7];
    const float* b3 = (const float*)d_in[8];
    float* out = (float*)d_out;

    (void)in_sizes; (void)n_in; (void)out_size;

    if (ws_size >= WS_NEED) {
        unsigned char* ws = (unsigned char*)d_ws;
        constexpr int PACK_THREADS =
            NE*16*32*64 + NE*16*32*64 + NE*32*64 + NE*NH*NH/8;
        pack_weights<<<(PACK_THREADS + 255)/256, 256, 0, stream>>>(W1, W2, W3, cat_ids, ws);
        tau_gemv<<<NB, 256, 0, stream>>>(timesteps, cat_ids, b2, ws);
        me_enc_mfma9<<<NB, 1024, 0, stream>>>(actions, cat_ids, b1, b3, ws, out);
    } else {
        me_enc_fused<<<NB, 512, 0, stream>>>(actions, timesteps, cat_ids,
                                             W1, b1, W2, b2, W3, b3, out);
    }
}

// Round 12
// 63.088 us; speedup vs baseline: 1.0179x; 1.0020x over previous
//
#include <hip/hip_runtime.h>

typedef __attribute__((ext_vector_type(8))) short bf16x8;
typedef __attribute__((ext_vector_type(4))) float f32x4;

namespace {
constexpr int NB = 256, NT = 64, NA = 32, NH = 512, NE = 16;
constexpr int ATS = 64 * 40;       // ushorts per ks-tile of A (row pad 40)

// workspace layout (bytes)
constexpr size_t W1P_OFF  = 0;
constexpr size_t W1P_SZ   = (size_t)NE * 32 * 64 * 16;         //    524,288
constexpr size_t W2AP_OFF = W1P_OFF + W1P_SZ;
constexpr size_t W2AP_SZ  = (size_t)NE * 16 * 32 * 64 * 16;    //  8,388,608
constexpr size_t W3P_OFF  = W2AP_OFF + W2AP_SZ;
constexpr size_t W3P_SZ   = (size_t)NE * 16 * 32 * 64 * 16;    //  8,388,608
constexpr size_t W2TP_OFF = W3P_OFF + W3P_SZ;
constexpr size_t W2TP_SZ  = (size_t)NE * NH * NH * 2;          //  8,388,608
constexpr size_t TAUC_OFF = W2TP_OFF + W2TP_SZ;
constexpr size_t TAUC_SZ  = (size_t)NB * NH * 4;               //    524,288
constexpr size_t PERM_OFF = TAUC_OFF + TAUC_SZ;
constexpr size_t WS_NEED  = PERM_OFF + (size_t)NB * 4;         // ~25.7 MiB
}

__device__ __forceinline__ unsigned f2bf(float x) {
    union { float f; unsigned u; } v; v.f = x;
    return (v.u + 0x7FFFu + ((v.u >> 16) & 1u)) >> 16;   // RNE, low 16 bits valid
}
__device__ __forceinline__ float bf2f(unsigned u) {   // low 16 bits = bf16
    union { unsigned u; float f; } v; v.u = u << 16;
    return v.f;
}
__device__ __forceinline__ f32x4 MFMA(bf16x8 a, bf16x8 b, f32x4 c) {
    return __builtin_amdgcn_mfma_f32_16x16x32_bf16(a, b, c, 0, 0, 0);
}

// ---------------------------------------------------------------------------
// pack_weights: f32 -> bf16. W1/W2a/W3 as MFMA-B fragments [cat][ks][nt][lane]
// (lane holds W[kbase+(lane>>4)*8+j][nt*16+(lane&15)], j=0..7). W2 tau-half
// (rows 512..1023) row-major bf16 [cat][k][c] for the tau GEMV.
// Block 0 additionally computes the cat-sorted permutation.
// ---------------------------------------------------------------------------
__global__ void pack_weights(const float* __restrict__ W1,
                             const float* __restrict__ W2,
                             const float* __restrict__ W3,
                             const int*   __restrict__ cat_ids,
                             unsigned char* __restrict__ ws)
{
    const int idx = blockIdx.x * 256 + threadIdx.x;
    constexpr int NF2 = NE * 16 * 32 * 64;    // 524,288  (W2 a_emb half)
    constexpr int NF3 = NE * 16 * 32 * 64;    // 524,288
    constexpr int NF1 = NE * 32 * 64;         //  32,768
    constexpr int NW2T = NE * NH * NH / 8;    // 524,288

    if (idx < NF2 + NF3 + NF1) {
        const float* src;
        uint4* dst;
        int fi, kbase;
        if (idx < NF2) {
            fi = idx;
            kbase = ((fi >> 11) & 15) * 32;                  // rows 0..511
            src = W2 + (size_t)(fi >> 15) * 1024 * NH;
            dst = (uint4*)(ws + W2AP_OFF);
        } else if (idx < NF2 + NF3) {
            fi = idx - NF2;
            kbase = ((fi >> 11) & 15) * 32;
            src = W3 + (size_t)(fi >> 15) * NH * NH;
            dst = (uint4*)(ws + W3P_OFF);
        } else {
            fi = idx - NF2 - NF3;
            kbase = 0;
            src = W1 + (size_t)(fi >> 11) * NA * NH;
            dst = (uint4*)(ws + W1P_OFF);
        }
        const int lane = fi & 63;
        const int nt   = (fi >> 6) & 31;
        const int k0   = kbase + ((lane >> 4) << 3);
        const int n    = nt * 16 + (lane & 15);
        unsigned rr[4];
        #pragma unroll
        for (int p = 0; p < 4; ++p) {
            const unsigned lo = f2bf(src[(size_t)(k0 + 2*p    ) * NH + n]);
            const unsigned hi = f2bf(src[(size_t)(k0 + 2*p + 1) * NH + n]);
            rr[p] = lo | (hi << 16);
        }
        uint4 r; r.x = rr[0]; r.y = rr[1]; r.z = rr[2]; r.w = rr[3];
        dst[fi] = r;
    } else if (idx < NF2 + NF3 + NF1 + NW2T) {
        const int p   = idx - (NF2 + NF3 + NF1);
        const int cat = p >> 15;
        const int rem = p & 32767;
        const int k   = rem >> 6;              // 0..511 tau-half row
        const int c0  = (rem & 63) << 3;
        const float* src =
            W2 + (size_t)cat * 1024 * NH + (size_t)(NH + k) * NH + c0;
        const float4 a = ((const float4*)src)[0];
        const float4 b = ((const float4*)src)[1];
        uint4 r;
        r.x = f2bf(a.x) | (f2bf(a.y) << 16);
        r.y = f2bf(a.z) | (f2bf(a.w) << 16);
        r.z = f2bf(b.x) | (f2bf(b.y) << 16);
        r.w = f2bf(b.z) | (f2bf(b.w) << 16);
        ((uint4*)(ws + W2TP_OFF))[p] = r;      // row-major [cat][k][c]
    }

    if (blockIdx.x == 0) {
        __shared__ int cs[NB];
        const int bb = threadIdx.x;
        cs[bb] = cat_ids[bb];
        __syncthreads();
        const int my = cs[bb];
        int rank = 0;
        #pragma unroll 8
        for (int i = 0; i < NB; ++i) {
            const int c = cs[i];
            rank += (c < my) || (c == my && i < bb);
        }
        ((int*)(ws + PERM_OFF))[rank] = bb;
    }
}

// ---------------------------------------------------------------------------
// tau_gemv: tauc[b][c] = b2[cat][c] + sum_k tau_b[k] * W2tau[cat][k][c].
// One block per b, 256 threads, each owns a col-pair via u32 loads.
// ---------------------------------------------------------------------------
__global__ __launch_bounds__(256)
void tau_gemv(const float* __restrict__ timesteps,
              const int*   __restrict__ cat_ids,
              const float* __restrict__ b2,
              unsigned char* __restrict__ ws)
{
    __shared__ float tau_s[NH];
    const int b   = blockIdx.x;
    const int tid = threadIdx.x;
    const int cat = cat_ids[b];
    const float t = timesteps[b];

    #pragma unroll
    for (int q = 0; q < 2; ++q) {
        const int k = tid + q * 256;
        const int i = k & 255;
        const float f = __expf(-(float)i * 0.036118981f);   // ln(1e4)/255
        tau_s[k] = (k < 256) ? __sinf(t * f) : __cosf(t * f);
    }
    __syncthreads();

    const unsigned* __restrict__ w =
        (const unsigned*)(ws + W2TP_OFF) + (size_t)cat * (NH * NH / 2) + tid;
    float s0a = 0.f, s1a = 0.f, s0b = 0.f, s1b = 0.f;
    #pragma unroll 8
    for (int k = 0; k < NH; k += 2) {
        const unsigned u0 = w[(size_t)k * 256];
        const unsigned u1 = w[(size_t)(k + 1) * 256];
        const float t0 = tau_s[k], t1 = tau_s[k + 1];
        s0a += t0 * bf2f(u0 & 0xffffu);  s1a += t0 * bf2f(u0 >> 16);
        s0b += t1 * bf2f(u1 & 0xffffu);  s1b += t1 * bf2f(u1 >> 16);
    }
    const int c = 2 * tid;
    float* tauc = (float*)(ws + TAUC_OFF) + (size_t)b * NH;
    tauc[c]     = s0a + s0b + b2[cat * NH + c];
    tauc[c + 1] = s1a + s1b + b2[cat * NH + c + 1];
}

// ---------------------------------------------------------------------------
// Fused MFMA kernel. Grid 256 (1 b per block/CU), 1024 threads = 16 waves,
// wave grid 1x16 (wave = 64 rows x 32 cols): every B-fragment loaded exactly
// once per block, 4 waves/SIMD. A in LDS as [ks][64 rows][40] ushort tiles:
// bank = (20*lr + 4*lg) % 32 -> exact 2-way (free); wave wn writes exactly
// ks-tile wn. 32-step B-stream (16 W2a + 16 W3), asm depth-5 pipeline,
// vmcnt(8) steady / 6,4,2,0 tail. Swish in place (single A buffer, 82 KB).
// ---------------------------------------------------------------------------
__global__ __launch_bounds__(1024, 4)
void me_enc_mfma9(const float* __restrict__ actions,
                  const int*   __restrict__ cat_ids,
                  const float* __restrict__ b1,
                  const float* __restrict__ b3,
                  const unsigned char* __restrict__ ws,
                  float* __restrict__ out)
{
    __shared__ unsigned short A_lds[16 * ATS];   // 81,920 B

    const int bid  = blockIdx.x;
    const int tid  = threadIdx.x;
    const int lane = tid & 63;
    const int wn   = tid >> 6;          // 0..15: 32-col slice (= own ks tile)
    const int lr   = lane & 15;
    const int lg   = lane >> 4;
    const int col0 = wn * 32;
    const bool loLane = (lane & 1) == 0;

    const int sidx = ((bid & 7) << 5) | (bid >> 3);   // same-cat -> same XCD
    const int* __restrict__ perm = (const int*)(ws + PERM_OFF);
    const int b   = perm[sidx];
    const int cat = cat_ids[b];

    const uint4* __restrict__ wp2 =
        (const uint4*)(ws + W2AP_OFF) + (size_t)cat * 16 * 2048 + (size_t)(2 * wn) * 64 + lane;
    const uint4* __restrict__ wp3 =
        (const uint4*)(ws + W3P_OFF) + (size_t)cat * 16 * 2048 + (size_t)(2 * wn) * 64 + lane;

    // ---- compiler-managed global loads ----
    float bias1[2], bias3[2], tauc_i[2];
    const float* __restrict__ taucp = (const float*)(ws + TAUC_OFF) + (size_t)b * NH;
    #pragma unroll
    for (int j = 0; j < 2; ++j) {
        const int c = col0 + j * 16 + lr;
        bias1[j]  = b1[cat * NH + c];
        bias3[j]  = b3[cat * NH + c];
        tauc_i[j] = taucp[c];
    }
    const uint4* __restrict__ w1p =
        (const uint4*)(ws + W1P_OFF) + (size_t)cat * 2048 + (size_t)(2 * wn) * 64 + lane;
    const uint4 w1f0 = w1p[0];
    const uint4 w1f1 = w1p[64];

    bf16x8 aact0, aact1, aact2, aact3;
    {
        bf16x8 tmp[4];
        #pragma unroll
        for (int mt = 0; mt < 4; ++mt) {
            const float* ap = actions + ((size_t)b * NT + mt * 16 + lr) * NA + lg * 8;
            const float4 a0 = ((const float4*)ap)[0];
            const float4 a1 = ((const float4*)ap)[1];
            bf16x8 v;
            v[0] = (short)f2bf(a0.x); v[1] = (short)f2bf(a0.y);
            v[2] = (short)f2bf(a0.z); v[3] = (short)f2bf(a0.w);
            v[4] = (short)f2bf(a1.x); v[5] = (short)f2bf(a1.y);
            v[6] = (short)f2bf(a1.z); v[7] = (short)f2bf(a1.w);
            tmp[mt] = v;
        }
        aact0 = tmp[0]; aact1 = tmp[1]; aact2 = tmp[2]; aact3 = tmp[3];
    }
    // Pin scalars consumed at/after the K-loop (scalar-only: R9 lesson).
    asm volatile("" :: "v"(bias3[0]), "v"(bias3[1]),
                       "v"(tauc_i[0]), "v"(tauc_i[1]));

    // ---- B pipeline: 5 slots x 2 frags, asm-issued ----
    uint4 buf0_0, buf0_1, buf1_0, buf1_1, buf2_0, buf2_1,
          buf3_0, buf3_1, buf4_0, buf4_1;

#define LOADB(S, kk)                                                            \
    if ((kk) < 32) {                                                            \
        const char* bp_ = (const char*)(((kk) < 16)                             \
            ? (wp2 + (size_t)(kk) * 2048)                                       \
            : (wp3 + (size_t)((kk) - 16) * 2048));                              \
        asm volatile("global_load_dwordx4 %0, %2, off\n\t"                      \
                     "global_load_dwordx4 %1, %2, off offset:1024"              \
                     : "=&v"(buf##S##_0), "=&v"(buf##S##_1)                     \
                     : "v"(bp_));                                               \
    }

    LOADB(0, 0) LOADB(1, 1)

    f32x4 acc[4][2];

    // ---- P1: layer 1 -> A_lds (packed u32 writes into own ks-tile) ----
    #pragma unroll
    for (int j = 0; j < 2; ++j) {
        const f32x4 v = {bias1[j], bias1[j], bias1[j], bias1[j]};
        #pragma unroll
        for (int mt = 0; mt < 4; ++mt) acc[mt][j] = v;
    }
    {
        union { uint4 u; bf16x8 v; } u0, u1;
        u0.u = w1f0; u1.u = w1f1;
        acc[0][0]=MFMA(aact0,u0.v,acc[0][0]); acc[1][0]=MFMA(aact1,u0.v,acc[1][0]);
        acc[2][0]=MFMA(aact2,u0.v,acc[2][0]); acc[3][0]=MFMA(aact3,u0.v,acc[3][0]);
        acc[0][1]=MFMA(aact0,u1.v,acc[0][1]); acc[1][1]=MFMA(aact1,u1.v,acc[1][1]);
        acc[2][1]=MFMA(aact2,u1.v,acc[2][1]); acc[3][1]=MFMA(aact3,u1.v,acc[3][1]);
    }
    unsigned* __restrict__ A32 = (unsigned*)A_lds;
    #pragma unroll
    for (int mt = 0; mt < 4; ++mt)
        #pragma unroll
        for (int j = 0; j < 2; ++j)
            #pragma unroll
            for (int r = 0; r < 4; ++r) {
                const float v  = acc[mt][j][r];
                const float vn = __shfl_xor(v, 1);
                if (loLane)
                    A32[(wn * ATS + (mt*16 + lg*4 + r) * 40 + j*16 + lr) >> 1] =
                        f2bf(v) | (f2bf(vn) << 16);
            }

    LOADB(2, 2) LOADB(3, 3) LOADB(4, 4)

    // ---- init acc for layer 2 (tauc already includes b2 + tau@W2tau) ----
    #pragma unroll
    for (int j = 0; j < 2; ++j) {
        const f32x4 v = {tauc_i[j], tauc_i[j], tauc_i[j], tauc_i[j]};
        #pragma unroll
        for (int mt = 0; mt < 4; ++mt) acc[mt][j] = v;
    }

    asm volatile("s_waitcnt lgkmcnt(0)" ::: "memory");
    __builtin_amdgcn_sched_barrier(0);
    __builtin_amdgcn_s_barrier();          // a_emb visible to all waves
    __builtin_amdgcn_sched_barrier(0);

#define STEPX(S, kk, VM)                                                        \
    {                                                                           \
        asm volatile("s_waitcnt vmcnt(" #VM ")");                               \
        __builtin_amdgcn_sched_barrier(0);                                      \
        const int ko_ = ((kk) & 15) * ATS + lg * 8;                             \
        const bf16x8 af0 = *(const bf16x8*)&A_lds[ko_ + (lr     ) * 40];        \
        const bf16x8 af1 = *(const bf16x8*)&A_lds[ko_ + (lr + 16) * 40];        \
        const bf16x8 af2 = *(const bf16x8*)&A_lds[ko_ + (lr + 32) * 40];        \
        const bf16x8 af3 = *(const bf16x8*)&A_lds[ko_ + (lr + 48) * 40];        \
        union { uint4 u; bf16x8 v; } w0_, w1_;                                  \
        w0_.u = buf##S##_0; w1_.u = buf##S##_1;                                 \
        acc[0][0] = MFMA(af0, w0_.v, acc[0][0]);                                \
        acc[1][0] = MFMA(af1, w0_.v, acc[1][0]);                                \
        acc[2][0] = MFMA(af2, w0_.v, acc[2][0]);                                \
        acc[3][0] = MFMA(af3, w0_.v, acc[3][0]);                                \
        acc[0][1] = MFMA(af0, w1_.v, acc[0][1]);                                \
        acc[1][1] = MFMA(af1, w1_.v, acc[1][1]);                                \
        acc[2][1] = MFMA(af2, w1_.v, acc[2][1]);                                \
        acc[3][1] = MFMA(af3, w1_.v, acc[3][1]);                                \
        LOADB(S, (kk) + 5)                                                      \
    }

    // ---- layer 2: steps 0..15 (A @ W2a, acc starts at tauc) ----
    STEPX(0, 0,8) STEPX(1, 1,8) STEPX(2, 2,8) STEPX(3, 3,8) STEPX(4, 4,8)
    STEPX(0, 5,8) STEPX(1, 6,8) STEPX(2, 7,8) STEPX(3, 8,8) STEPX(4, 9,8)
    STEPX(0,10,8) STEPX(1,11,8) STEPX(2,12,8) STEPX(3,13,8) STEPX(4,14,8)
    STEPX(0,15,8)

    // ---- swish in place: all reads done -> barrier -> write -> barrier ----
    asm volatile("s_waitcnt lgkmcnt(0)" ::: "memory");
    __builtin_amdgcn_sched_barrier(0);
    __builtin_amdgcn_s_barrier();          // all waves done reading a_emb
    __builtin_amdgcn_sched_barrier(0);
    #pragma unroll
    for (int mt = 0; mt < 4; ++mt)
        #pragma unroll
        for (int j = 0; j < 2; ++j)
            #pragma unroll
            for (int r = 0; r < 4; ++r) {
                const float h  = acc[mt][j][r];
                const float sw = h / (1.f + __expf(-h));
                const float swn = __shfl_xor(sw, 1);
                if (loLane)
                    A32[(wn * ATS + (mt*16 + lg*4 + r) * 40 + j*16 + lr) >> 1] =
                        f2bf(sw) | (f2bf(swn) << 16);
            }
    #pragma unroll
    for (int j = 0; j < 2; ++j) {
        const f32x4 v = {bias3[j], bias3[j], bias3[j], bias3[j]};
        #pragma unroll
        for (int mt = 0; mt < 4; ++mt) acc[mt][j] = v;
    }
    asm volatile("s_waitcnt lgkmcnt(0)" ::: "memory");
    __builtin_amdgcn_sched_barrier(0);
    __builtin_amdgcn_s_barrier();          // swish visible (W3 loads in flight)
    __builtin_amdgcn_sched_barrier(0);

    // ---- layer 3: steps 16..31 (A @ W3), tail vmcnt 6/4/2/0 ----
    STEPX(1,16,8) STEPX(2,17,8) STEPX(3,18,8) STEPX(4,19,8) STEPX(0,20,8)
    STEPX(1,21,8) STEPX(2,22,8) STEPX(3,23,8) STEPX(4,24,8) STEPX(0,25,8)
    STEPX(1,26,8) STEPX(2,27,8) STEPX(3,28,6) STEPX(4,29,4) STEPX(0,30,2)
    STEPX(1,31,0)

#undef STEPX
#undef LOADB

    // ---- epilogue ----
    #pragma unroll
    for (int mt = 0; mt < 4; ++mt)
        #pragma unroll
        for (int j = 0; j < 2; ++j)
            #pragma unroll
            for (int r = 0; r < 4; ++r)
                out[((size_t)b * NT + mt*16 + lg*4 + r) * NH + col0 + j*16 + lr] =
                    acc[mt][j][r];
}

// ---------------------------------------------------------------------------
// Fallback (f32, no workspace) if ws is too small.
// ---------------------------------------------------------------------------
__global__ __launch_bounds__(512, 2)
void me_enc_fused(const float* __restrict__ actions,
                  const float* __restrict__ timesteps,
                  const int*   __restrict__ cat_ids,
                  const float* __restrict__ W1,
                  const float* __restrict__ b1,
                  const float* __restrict__ W2,
                  const float* __restrict__ b2,
                  const float* __restrict__ W3,
                  const float* __restrict__ b3,
                  float* __restrict__ out)
{
    __shared__ float tau_s[NH];
    __shared__ float tauc_s[NH];
    __shared__ float act_s[16 * NA];
    __shared__ float buf_s[16][NH];

    const int b   = blockIdx.x;
    const int tid = threadIdx.x;
    const int cat = cat_ids[b];
    const float t = timesteps[b];

    const float* __restrict__ W1c = W1 + (size_t)cat * NA * NH;
    const float* __restrict__ W2c = W2 + (size_t)cat * 2 * NH * NH;
    const float* __restrict__ W2t = W2c + (size_t)NH * NH;
    const float* __restrict__ W3c = W3 + (size_t)cat * NH * NH;

    {
        const int i = tid & 255;
        const float f   = __expf(-(float)i * 0.036118981f);
        const float ang = t * f;
        tau_s[tid] = (tid < 256) ? __sinf(ang) : __cosf(ang);
    }
    __syncthreads();
    {
        float c0 = 0.f;
        for (int k = 0; k < NH; ++k)
            c0 += tau_s[k] * W2t[(size_t)k * NH + tid];
        tauc_s[tid] = b2[cat * NH + tid] + c0;
    }
    const float b1v = b1[cat * NH + tid];
    const int j2  = tid & 255;
    const int tl0 = (tid >> 8) * 8;
    const float b3v0 = b3[cat * NH + j2];
    const float b3v1 = b3[cat * NH + j2 + 256];
    const size_t obase = (size_t)b * NT * NH;
    float acc0[8], acc1[8];

    for (int t0 = 0; t0 < NT; t0 += 16) {
        act_s[tid] = actions[(size_t)b*NT*NA + (size_t)(t0 + (tid >> 5))*NA + (tid & 31)];
        __syncthreads();
        {
            float a_[16];
            #pragma unroll
            for (int l = 0; l < 16; ++l) a_[l] = b1v;
            for (int a = 0; a < NA; ++a) {
                const float w = W1c[(size_t)a * NH + tid];
                #pragma unroll
                for (int l = 0; l < 16; ++l) a_[l] += act_s[l*NA + a] * w;
            }
            #pragma unroll
            for (int l = 0; l < 16; ++l) buf_s[l][tid] = a_[l];
        }
        __syncthreads();
        {
            const float tc0 = tauc_s[j2], tc1 = tauc_s[j2 + 256];
            #pragma unroll
            for (int l = 0; l < 8; ++l) { acc0[l] = tc0; acc1[l] = tc1; }
            for (int k = 0; k < NH; ++k) {
                const float wa = W2c[(size_t)k*NH + j2];
                const float wb = W2c[(size_t)k*NH + j2 + 256];
                #pragma unroll
                for (int l = 0; l < 8; ++l) {
                    const float av = buf_s[tl0 + l][k];
                    acc0[l] += av * wa; acc1[l] += av * wb;
                }
            }
        }
        __syncthreads();
        #pragma unroll
        for (int l = 0; l < 8; ++l) {
            buf_s[tl0 + l][j2]       = acc0[l] / (1.f + __expf(-acc0[l]));
            buf_s[tl0 + l][j2 + 256] = acc1[l] / (1.f + __expf(-acc1[l]));
        }
        __syncthreads();
        {
            #pragma unroll
            for (int l = 0; l < 8; ++l) { acc0[l] = b3v0; acc1[l] = b3v1; }
            for (int k = 0; k < NH; ++k) {
                const float wa = W3c[(size_t)k*NH + j2];
                const float wb = W3c[(size_t)k*NH + j2 + 256];
                #pragma unroll
                for (int l = 0; l < 8; ++l) {
                    const float av = buf_s[tl0 + l][k];
                    acc0[l] += av * wa; acc1[l] += av * wb;
                }
            }
            #pragma unroll
            for (int l = 0; l < 8; ++l) {
                out[obase + (size_t)(t0 + tl0 + l)*NH + j2]       = acc0[l];
                out[obase + (size_t)(t0 + tl0 + l)*NH + j2 + 256] = acc1[l];
            }
        }
        __syncthreads();
    }
}

extern "C" void kernel_launch(void* const* d_in, const int* in_sizes, int n_in,
                              void* d_out, int out_size, void* d_ws, size_t ws_size,
                              hipStream_t stream)
{
    const float* actions   = (const float*)d_in[0];
    const float* timesteps = (const float*)d_in[1];
    const int*   cat_ids   = (const int*)  d_in[2];
    const float* W1 = (const float*)d_in[3];
    const float* b1 = (const float*)d_in[4];
    const float* W2 = (const float*)d_in[5];
    const float* b2 = (const float*)d_in[6];
    const float* W3 = (const float*)d_in[7];
    const float* b3 = (const float*)d_in[8];
    float* out = (float*)d_out;

    (void)in_sizes; (void)n_in; (void)out_size;

    if (ws_size >= WS_NEED) {
        unsigned char* ws = (unsigned char*)d_ws;
        constexpr int PACK_THREADS =
            NE*16*32*64 + NE*16*32*64 + NE*32*64 + NE*NH*NH/8;
        pack_weights<<<(PACK_THREADS + 255)/256, 256, 0, stream>>>(W1, W2, W3, cat_ids, ws);
        tau_gemv<<<NB, 256, 0, stream>>>(timesteps, cat_ids, b2, ws);
        me_enc_mfma9<<<NB, 1024, 0, stream>>>(actions, cat_ids, b1, b3, ws, out);
    } else {
        me_enc_fused<<<NB, 512, 0, stream>>>(actions, timesteps, cat_ids,
                                             W1, b1, W2, b2, W3, b3, out);
    }
}

// Round 15
// 47.195 us; speedup vs baseline: 1.3606x; 1.3367x over previous
//
#include <hip/hip_runtime.h>

typedef __attribute__((ext_vector_type(8))) short bf16x8;
typedef __attribute__((ext_vector_type(4))) float f32x4;

namespace {
constexpr int NB = 256, NT = 64, NA = 32, NH = 512, NE = 16;
constexpr int NK2 = 32;            // layer-2 K-steps (K=1024: 16 tau + 16 a_emb)
constexpr int NK3 = 16;            // layer-3 K-steps (K=512)
constexpr int NK  = NK2 + NK3;     // unified B-stream length (48)
constexpr int LDAu = 520;          // A_lds row stride (ushorts)

// workspace layout (bytes)
constexpr size_t W1P_OFF = 0;
constexpr size_t W1P_SZ  = (size_t)NE * 32 * 64 * 16;          //    524,288
constexpr size_t W2P_OFF = W1P_OFF + W1P_SZ;
constexpr size_t W2P_SZ  = (size_t)NE * NK2 * 32 * 64 * 16;    // 16,777,216
constexpr size_t W3P_OFF = W2P_OFF + W2P_SZ;
constexpr size_t W3P_SZ  = (size_t)NE * NK3 * 32 * 64 * 16;    //  8,388,608
constexpr size_t PERM_OFF = W3P_OFF + W3P_SZ;
constexpr size_t WS_NEED  = PERM_OFF + (size_t)NB * 4;         // ~24.5 MiB
}

__device__ __forceinline__ unsigned f2bf(float x) {
    union { float f; unsigned u; } v; v.f = x;
    return (v.u + 0x7FFFu + ((v.u >> 16) & 1u)) >> 16;   // RNE, low 16 bits valid
}
__device__ __forceinline__ f32x4 MFMA(bf16x8 a, bf16x8 b, f32x4 c) {
    return __builtin_amdgcn_mfma_f32_16x16x32_bf16(a, b, c, 0, 0, 0);
}

// ---------------------------------------------------------------------------
// pack_weights: f32 -> bf16 MFMA-B fragments, [cat][ks][nt][lane] 16B each.
// Lane holds W[kbase + (lane>>4)*8 + j][nt*16 + (lane&15)], j=0..7.
// W2 k-step order: ks 0..15 = tau rows (512..1023), ks 16..31 = rows 0..511.
// Block 0 additionally computes the cat-sorted permutation.
// ---------------------------------------------------------------------------
__global__ void pack_weights(const float* __restrict__ W1,
                             const float* __restrict__ W2,
                             const float* __restrict__ W3,
                             const int*   __restrict__ cat_ids,
                             unsigned char* __restrict__ ws)
{
    const int idx = blockIdx.x * 256 + threadIdx.x;
    constexpr int NF2 = NE * NK2 * 32 * 64;   // 1,048,576
    constexpr int NF3 = NE * NK3 * 32 * 64;   //   524,288
    constexpr int NF1 = NE * 32 * 64;         //    32,768

    const float* src = nullptr;
    uint4* dst = nullptr;
    int fi = 0, kbase = 0;
    bool have = true;
    if (idx < NF2) {
        fi = idx;
        const int ks = (fi >> 11) & 31;
        kbase = (ks < 16) ? (512 + ks * 32) : ((ks - 16) * 32);
        src = W2 + (size_t)(fi >> 16) * 1024 * NH;
        dst = (uint4*)(ws + W2P_OFF);
    } else if (idx < NF2 + NF3) {
        fi = idx - NF2;
        kbase = ((fi >> 11) & 15) * 32;
        src = W3 + (size_t)(fi >> 15) * NH * NH;
        dst = (uint4*)(ws + W3P_OFF);
    } else if (idx < NF2 + NF3 + NF1) {
        fi = idx - NF2 - NF3;
        kbase = 0;
        src = W1 + (size_t)(fi >> 11) * NA * NH;
        dst = (uint4*)(ws + W1P_OFF);
    } else have = false;

    if (have) {
        const int lane = fi & 63;
        const int nt   = (fi >> 6) & 31;
        const int k0   = kbase + ((lane >> 4) << 3);
        const int n    = nt * 16 + (lane & 15);
        unsigned rr[4];
        #pragma unroll
        for (int p = 0; p < 4; ++p) {
            const unsigned lo = f2bf(src[(size_t)(k0 + 2*p    ) * NH + n]);
            const unsigned hi = f2bf(src[(size_t)(k0 + 2*p + 1) * NH + n]);
            rr[p] = lo | (hi << 16);
        }
        uint4 r; r.x = rr[0]; r.y = rr[1]; r.z = rr[2]; r.w = rr[3];
        dst[fi] = r;
    }

    if (blockIdx.x == 0) {
        __shared__ int cs[NB];
        const int bb = threadIdx.x;
        cs[bb] = cat_ids[bb];
        __syncthreads();
        const int my = cs[bb];
        int rank = 0;
        #pragma unroll 8
        for (int i = 0; i < NB; ++i) {
            const int c = cs[i];
            rank += (c < my) || (c == my && i < bb);
        }
        ((int*)(ws + PERM_OFF))[rank] = bb;
    }
}

// ---------------------------------------------------------------------------
// Fused MFMA kernel (R8 structure, coarsened fences). Grid 256, 1024 threads
// = 16 waves, wave grid 1x16 (wave = 64 rows x 32 cols): every B-fragment
// loaded exactly once per block. 48-step unified B-stream with depth-6 asm
// register pipeline; fences at REGION (2-step) granularity: one vmcnt(8) +
// one sched_barrier(0) per 8 ds_reads + 16 MFMAs, so step-b's LDS reads
// schedule under step-a's MFMAs.
// ---------------------------------------------------------------------------
__global__ __launch_bounds__(1024, 4)
void me_enc_mfma12(const float* __restrict__ actions,
                   const float* __restrict__ timesteps,
                   const int*   __restrict__ cat_ids,
                   const float* __restrict__ b1,
                   const float* __restrict__ b2,
                   const float* __restrict__ b3,
                   const unsigned char* __restrict__ ws,
                   float* __restrict__ out)
{
    __shared__ unsigned short A0[NT * LDAu];            // 66,560 B (a_emb)
    __shared__ unsigned short A1[NT * LDAu];            // 66,560 B (swish)
    __shared__ alignas(16) unsigned tau_u32[NH / 2];    //  1,024 B

    const int bid  = blockIdx.x;
    const int tid  = threadIdx.x;
    const int lane = tid & 63;
    const int wn   = tid >> 6;          // 0..15: 32-col slice
    const int lr   = lane & 15;
    const int lg   = lane >> 4;
    const int col0 = wn * 32;

    // XCD-contiguous sorted order: same-cat blocks -> same XCD L2
    const int sidx = ((bid & 7) << 5) | (bid >> 3);
    const int* __restrict__ perm = (const int*)(ws + PERM_OFF);
    const int b    = perm[sidx];
    const int cat  = cat_ids[b];
    const float t  = timesteps[b];

    const uint4* __restrict__ wp2 =
        (const uint4*)(ws + W2P_OFF) + (size_t)cat * NK2 * 2048 + (size_t)(2 * wn) * 64 + lane;
    const uint4* __restrict__ wp3 =
        (const uint4*)(ws + W3P_OFF) + (size_t)cat * NK3 * 2048 + (size_t)(2 * wn) * 64 + lane;

    // ---- tau(t) -> bf16 pairs ----
    if (tid < 256) {
        const int i0 = (2 * tid) & 255, i1 = i0 + 1;
        const float f0 = __expf(-(float)i0 * 0.036118981f);   // ln(1e4)/255
        const float f1 = __expf(-(float)i1 * 0.036118981f);
        float v0, v1;
        if (tid < 128) { v0 = __sinf(t * f0); v1 = __sinf(t * f1); }
        else           { v0 = __cosf(t * f0); v1 = __cosf(t * f1); }
        tau_u32[tid] = f2bf(v0) | (f2bf(v1) << 16);
    }

    // ---- biases, W1 fragments, actions (compiler-managed loads) ----
    float bias1[2], bias2[2], bias3[2];
    #pragma unroll
    for (int j = 0; j < 2; ++j) {
        const int c = cat * NH + col0 + j * 16 + lr;
        bias1[j] = b1[c]; bias2[j] = b2[c]; bias3[j] = b3[c];
    }
    const uint4* __restrict__ w1p =
        (const uint4*)(ws + W1P_OFF) + (size_t)cat * 2048 + (size_t)(2 * wn) * 64 + lane;
    const uint4 w1f0 = w1p[0];
    const uint4 w1f1 = w1p[64];

    bf16x8 aact[4];
    #pragma unroll
    for (int mt = 0; mt < 4; ++mt) {
        const float* ap = actions + ((size_t)b * NT + mt * 16 + lr) * NA + lg * 8;
        const float4 a0 = ((const float4*)ap)[0];
        const float4 a1 = ((const float4*)ap)[1];
        bf16x8 v;
        v[0] = (short)f2bf(a0.x); v[1] = (short)f2bf(a0.y);
        v[2] = (short)f2bf(a0.z); v[3] = (short)f2bf(a0.w);
        v[4] = (short)f2bf(a1.x); v[5] = (short)f2bf(a1.y);
        v[6] = (short)f2bf(a1.z); v[7] = (short)f2bf(a1.w);
        aact[mt] = v;
    }

    // Pin scalar values consumed at/after the K-loop so the compiler's own
    // vmcnt waits for them land HERE, not inside the asm pipeline.
    asm volatile("" :: "v"(bias2[0]), "v"(bias2[1]),
                       "v"(bias3[0]), "v"(bias3[1]));

    __syncthreads();   // tau visible to all waves (drains everything pre-pipeline)

    // depth-6 B pipeline, named registers, asm-issued loads
    uint4 buf0_0, buf0_1, buf1_0, buf1_1, buf2_0, buf2_1,
          buf3_0, buf3_1, buf4_0, buf4_1, buf5_0, buf5_1;

#define LOADB(S, kk)                                                            \
    if ((kk) < NK) {                                                            \
        const char* bp_ = (const char*)(((kk) < NK2)                            \
            ? (const void*)(wp2 + (size_t)(kk) * 2048)                          \
            : (const void*)(wp3 + (size_t)((kk) - NK2) * 2048));                \
        asm volatile("global_load_dwordx4 %0, %2, off\n\t"                      \
                     "global_load_dwordx4 %1, %2, off offset:1024"              \
                     : "=&v"(buf##S##_0), "=&v"(buf##S##_1)                     \
                     : "v"(bp_));                                               \
    }

    // prologue: 6 slots (12 loads) in flight before any compute consumes them
    LOADB(0, 0) LOADB(1, 1) LOADB(2, 2) LOADB(3, 3) LOADB(4, 4) LOADB(5, 5)

    f32x4 acc[4][2];

    // ---- P1: layer 1 -> A0 (bf16 a_emb); covers prologue load latency ----
    #pragma unroll
    for (int j = 0; j < 2; ++j) {
        const f32x4 v = {bias1[j], bias1[j], bias1[j], bias1[j]};
        #pragma unroll
        for (int mt = 0; mt < 4; ++mt) acc[mt][j] = v;
    }
    {
        union { uint4 u; bf16x8 v; } w0_, w1_;
        w0_.u = w1f0; w1_.u = w1f1;
        #pragma unroll
        for (int mt = 0; mt < 4; ++mt) {
            acc[mt][0] = MFMA(aact[mt], w0_.v, acc[mt][0]);
            acc[mt][1] = MFMA(aact[mt], w1_.v, acc[mt][1]);
        }
    }
    #pragma unroll
    for (int mt = 0; mt < 4; ++mt)
        #pragma unroll
        for (int j = 0; j < 2; ++j)
            #pragma unroll
            for (int r = 0; r < 4; ++r)
                A0[(mt*16 + lg*4 + r) * LDAu + col0 + j*16 + lr] =
                    (unsigned short)f2bf(acc[mt][j][r]);

    // ---- init acc for P2 ----
    #pragma unroll
    for (int j = 0; j < 2; ++j) {
        const f32x4 v = {bias2[j], bias2[j], bias2[j], bias2[j]};
        #pragma unroll
        for (int mt = 0; mt < 4; ++mt) acc[mt][j] = v;
    }

    const unsigned short* __restrict__ tau_us = (const unsigned short*)tau_u32;

    // step body: 4 ds_reads (or tau broadcast) + 8 MFMAs, no fences
#define STEPBODY(S, kk)                                                         \
    {                                                                           \
        bf16x8 af0, af1, af2, af3;                                              \
        if ((kk) < 16) {                                                        \
            af0 = *(const bf16x8*)&tau_us[(kk) * 32 + lg * 8];                  \
            af1 = af0; af2 = af0; af3 = af0;                                    \
        } else if ((kk) < NK2) {                                                \
            const int ko_ = ((kk) - 16) * 32 + lg * 8;                          \
            af0 = *(const bf16x8*)&A0[(lr     ) * LDAu + ko_];                  \
            af1 = *(const bf16x8*)&A0[(lr + 16) * LDAu + ko_];                  \
            af2 = *(const bf16x8*)&A0[(lr + 32) * LDAu + ko_];                  \
            af3 = *(const bf16x8*)&A0[(lr + 48) * LDAu + ko_];                  \
        } else {                                                                \
            const int ko_ = ((kk) - NK2) * 32 + lg * 8;                         \
            af0 = *(const bf16x8*)&A1[(lr     ) * LDAu + ko_];                  \
            af1 = *(const bf16x8*)&A1[(lr + 16) * LDAu + ko_];                  \
            af2 = *(const bf16x8*)&A1[(lr + 32) * LDAu + ko_];                  \
            af3 = *(const bf16x8*)&A1[(lr + 48) * LDAu + ko_];                  \
        }                                                                       \
        union { uint4 u; bf16x8 v; } w0_, w1_;                                  \
        w0_.u = buf##S##_0; w1_.u = buf##S##_1;                                 \
        acc[0][0] = MFMA(af0, w0_.v, acc[0][0]);                                \
        acc[1][0] = MFMA(af1, w0_.v, acc[1][0]);                                \
        acc[2][0] = MFMA(af2, w0_.v, acc[2][0]);                                \
        acc[3][0] = MFMA(af3, w0_.v, acc[3][0]);                                \
        acc[0][1] = MFMA(af0, w1_.v, acc[0][1]);                                \
        acc[1][1] = MFMA(af1, w1_.v, acc[1][1]);                                \
        acc[2][1] = MFMA(af2, w1_.v, acc[2][1]);                                \
        acc[3][1] = MFMA(af3, w1_.v, acc[3][1]);                                \
    }

    // region: one counted wait + one fence per TWO steps
#define REGION(Sa, Sb, ka, VM)                                                  \
    asm volatile("s_waitcnt vmcnt(" #VM ")");                                   \
    __builtin_amdgcn_sched_barrier(0);                                          \
    STEPBODY(Sa, (ka))      LOADB(Sa, (ka) + 6)                                 \
    STEPBODY(Sb, (ka) + 1)  LOADB(Sb, (ka) + 7)

    // ---- tau phase: steps 0..15 ----
    REGION(0,1, 0,8) REGION(2,3, 2,8) REGION(4,5, 4,8) REGION(0,1, 6,8)
    REGION(2,3, 8,8) REGION(4,5,10,8) REGION(0,1,12,8) REGION(2,3,14,8)

    // ---- a_emb visible barrier (B loads stay in flight) ----
    asm volatile("s_waitcnt lgkmcnt(0)" ::: "memory");
    __builtin_amdgcn_sched_barrier(0);
    __builtin_amdgcn_s_barrier();
    __builtin_amdgcn_sched_barrier(0);

    // ---- a_emb phase: steps 16..31 ----
    REGION(4,5,16,8) REGION(0,1,18,8) REGION(2,3,20,8) REGION(4,5,22,8)
    REGION(0,1,24,8) REGION(2,3,26,8) REGION(4,5,28,8) REGION(0,1,30,8)

    // ---- swish -> A1, acc = bias3, barrier (W3 loads in flight) ----
    #pragma unroll
    for (int mt = 0; mt < 4; ++mt)
        #pragma unroll
        for (int j = 0; j < 2; ++j)
            #pragma unroll
            for (int r = 0; r < 4; ++r) {
                const float h  = acc[mt][j][r];
                const float sw = h / (1.f + __expf(-h));
                A1[(mt*16 + lg*4 + r) * LDAu + col0 + j*16 + lr] =
                    (unsigned short)f2bf(sw);
            }
    #pragma unroll
    for (int j = 0; j < 2; ++j) {
        const f32x4 v = {bias3[j], bias3[j], bias3[j], bias3[j]};
        #pragma unroll
        for (int mt = 0; mt < 4; ++mt) acc[mt][j] = v;
    }
    asm volatile("s_waitcnt lgkmcnt(0)" ::: "memory");
    __builtin_amdgcn_sched_barrier(0);
    __builtin_amdgcn_s_barrier();
    __builtin_amdgcn_sched_barrier(0);

    // ---- swish phase: steps 32..47 (tail vmcnt 8/4/0) ----
    REGION(2,3,32,8) REGION(4,5,34,8) REGION(0,1,36,8) REGION(2,3,38,8)
    REGION(4,5,40,8) REGION(0,1,42,8) REGION(2,3,44,4) REGION(4,5,46,0)

#undef REGION
#undef STEPBODY
#undef LOADB

    // ---- epilogue: out = acc ----
    #pragma unroll
    for (int mt = 0; mt < 4; ++mt)
        #pragma unroll
        for (int j = 0; j < 2; ++j)
            #pragma unroll
            for (int r = 0; r < 4; ++r)
                out[((size_t)b * NT + mt*16 + lg*4 + r) * NH + col0 + j*16 + lr] =
                    acc[mt][j][r];
}

// ---------------------------------------------------------------------------
// Fallback (f32, no workspace) if ws is too small.
// ---------------------------------------------------------------------------
__global__ __launch_bounds__(512, 2)
void me_enc_fused(const float* __restrict__ actions,
                  const float* __restrict__ timesteps,
                  const int*   __restrict__ cat_ids,
                  const float* __restrict__ W1,
                  const float* __restrict__ b1,
                  const float* __restrict__ W2,
                  const float* __restrict__ b2,
                  const float* __restrict__ W3,
                  const float* __restrict__ b3,
                  float* __restrict__ out)
{
    __shared__ float tau_s[NH];
    __shared__ float tauc_s[NH];
    __shared__ float act_s[16 * NA];
    __shared__ float buf_s[16][NH];

    const int b   = blockIdx.x;
    const int tid = threadIdx.x;
    const int cat = cat_ids[b];
    const float t = timesteps[b];

    const float* __restrict__ W1c = W1 + (size_t)cat * NA * NH;
    const float* __restrict__ W2c = W2 + (size_t)cat * 2 * NH * NH;
    const float* __restrict__ W2t = W2c + (size_t)NH * NH;
    const float* __restrict__ W3c = W3 + (size_t)cat * NH * NH;

    {
        const int i = tid & 255;
        const float f   = __expf(-(float)i * 0.036118981f);
        const float ang = t * f;
        tau_s[tid] = (tid < 256) ? __sinf(ang) : __cosf(ang);
    }
    __syncthreads();
    {
        float c0 = 0.f;
        for (int k = 0; k < NH; ++k)
            c0 += tau_s[k] * W2t[(size_t)k * NH + tid];
        tauc_s[tid] = b2[cat * NH + tid] + c0;
    }
    const float b1v = b1[cat * NH + tid];
    const int j2  = tid & 255;
    const int tl0 = (tid >> 8) * 8;
    const float b3v0 = b3[cat * NH + j2];
    const float b3v1 = b3[cat * NH + j2 + 256];
    const size_t obase = (size_t)b * NT * NH;
    float acc0[8], acc1[8];

    for (int t0 = 0; t0 < NT; t0 += 16) {
        act_s[tid] = actions[(size_t)b*NT*NA + (size_t)(t0 + (tid >> 5))*NA + (tid & 31)];
        __syncthreads();
        {
            float a_[16];
            #pragma unroll
            for (int l = 0; l < 16; ++l) a_[l] = b1v;
            for (int a = 0; a < NA; ++a) {
                const float w = W1c[(size_t)a * NH + tid];
                #pragma unroll
                for (int l = 0; l < 16; ++l) a_[l] += act_s[l*NA + a] * w;
            }
            #pragma unroll
            for (int l = 0; l < 16; ++l) buf_s[l][tid] = a_[l];
        }
        __syncthreads();
        {
            const float tc0 = tauc_s[j2], tc1 = tauc_s[j2 + 256];
            #pragma unroll
            for (int l = 0; l < 8; ++l) { acc0[l] = tc0; acc1[l] = tc1; }
            for (int k = 0; k < NH; ++k) {
                const float wa = W2c[(size_t)k*NH + j2];
                const float wb = W2c[(size_t)k*NH + j2 + 256];
                #pragma unroll
                for (int l = 0; l < 8; ++l) {
                    const float av = buf_s[tl0 + l][k];
                    acc0[l] += av * wa; acc1[l] += av * wb;
                }
            }
        }
        __syncthreads();
        #pragma unroll
        for (int l = 0; l < 8; ++l) {
            buf_s[tl0 + l][j2]       = acc0[l] / (1.f + __expf(-acc0[l]));
            buf_s[tl0 + l][j2 + 256] = acc1[l] / (1.f + __expf(-acc1[l]));
        }
        __syncthreads();
        {
            #pragma unroll
            for (int l = 0; l < 8; ++l) { acc0[l] = b3v0; acc1[l] = b3v1; }
            for (int k = 0; k < NH; ++k) {
                const float wa = W3c[(size_t)k*NH + j2];
                const float wb = W3c[(size_t)k*NH + j2 + 256];
                #pragma unroll
                for (int l = 0; l < 8; ++l) {
                    const float av = buf_s[tl0 + l][k];
                    acc0[l] += av * wa; acc1[l] += av * wb;
                }
            }
            #pragma unroll
            for (int l = 0; l < 8; ++l) {
                out[obase + (size_t)(t0 + tl0 + l)*NH + j2]       = acc0[l];
                out[obase + (size_t)(t0 + tl0 + l)*NH + j2 + 256] = acc1[l];
            }
        }
        __syncthreads();
    }
}

extern "C" void kernel_launch(void* const* d_in, const int* in_sizes, int n_in,
                              void* d_out, int out_size, void* d_ws, size_t ws_size,
                              hipStream_t stream)
{
    const float* actions   = (const float*)d_in[0];
    const float* timesteps = (const float*)d_in[1];
    const int*   cat_ids   = (const int*)  d_in[2];
    const float* W1 = (const float*)d_in[3];
    const float* b1 = (const float*)d_in[4];
    const float* W2 = (const float*)d_in[5];
    const float* b2 = (const float*)d_in[6];
    const float* W3 = (const float*)d_in[7];
    const float* b3 = (const float*)d_in[8];
    float* out = (float*)d_out;

    (void)in_sizes; (void)n_in; (void)out_size;

    if (ws_size >= WS_NEED) {
        unsigned char* ws = (unsigned char*)d_ws;
        constexpr int PACK_THREADS = NE*NK2*32*64 + NE*NK3*32*64 + NE*32*64;
        pack_weights<<<(PACK_THREADS + 255)/256, 256, 0, stream>>>(W1, W2, W3, cat_ids, ws);
        me_enc_mfma12<<<NB, 1024, 0, stream>>>(actions, timesteps, cat_ids,
                                               b1, b2, b3, ws, out);
    } else {
        me_enc_fused<<<NB, 512, 0, stream>>>(actions, timesteps, cat_ids,
                                             W1, b1, W2, b2, W3, b3, out);
    }
}